// Round 5
// baseline (265.568 us; speedup 1.0000x reference)
//
#include <hip/hip_runtime.h>
#include <hip/hip_bf16.h>
#include <stdint.h>

typedef __attribute__((ext_vector_type(4))) float f32x4;
typedef __attribute__((ext_vector_type(8))) short short8;
typedef __attribute__((ext_vector_type(4))) unsigned short u16x4;
typedef unsigned short us;

#define DEV __device__ __forceinline__
#define MFMA16(a, b, c) __builtin_amdgcn_mfma_f32_16x16x32_bf16(a, b, c, 0, 0, 0)

DEV us f2b(float x) {
  union { float f; uint32_t u; } c; c.f = x;
  uint32_t r = (c.u + 0x7fffu + ((c.u >> 16) & 1u)) >> 16;
  return (us)r;
}
DEV float b2f(us x) {
  union { uint32_t u; float f; } c; c.u = ((uint32_t)x) << 16;
  return c.f;
}

DEV void gload_lds16(const void* g, void* l) {
  __builtin_amdgcn_global_load_lds((const __attribute__((address_space(1))) void*)g,
                                   (__attribute__((address_space(3))) void*)l, 16, 0, 0);
}

// ---------------- kernel 1: fp32 -> bf16 conversions ----------------
__global__ __launch_bounds__(256) void prep_k(
    const float* __restrict__ x, const float* __restrict__ wproj,
    const float* __restrict__ wg, const float* __restrict__ wo,
    us* __restrict__ Xbf, us* __restrict__ Wbf, us* __restrict__ Wobf) {
  int i = blockIdx.x * 256 + threadIdx.x;
  const float* src; us* dst;
  if (i < 524288)               { src = x     + (size_t)i * 4;                  dst = Xbf + (size_t)i * 4; }
  else if (i < 524288 + 786432) { int j = i - 524288;            src = wproj + (size_t)j * 4; dst = Wbf + (size_t)j * 4; }
  else if (i < 524288 + 786432 + 262144) { int j = i - (524288 + 786432); src = wg + (size_t)j * 4; dst = Wbf + 3145728 + (size_t)j * 4; }
  else                          { int j = i - (524288 + 786432 + 262144); src = wo + (size_t)j * 4; dst = Wobf + (size_t)j * 4; }
  f32x4 v = *(const f32x4*)src;
  u16x4 o; o.x = f2b(v.x); o.y = f2b(v.y); o.z = f2b(v.z); o.w = f2b(v.w);
  *(u16x4*)dst = o;
}

// ---------------- shared GEMM core (m97-style, 128x128) ----------------
DEV void gemm_stage(char* sm, const us* A, const us* Bw,
                    int tileMrow, int tileNrow, int buf, int kt, int lane, int wid) {
  const char* gA = (const char*)A;
  const char* gB = (const char*)Bw;
#pragma unroll
  for (int i = 0; i < 2; ++i) {
    int c = wid * 2 + i;
    int off = c * 1024 + lane * 16;
    int r = off >> 6, cb = off & 63;
    gload_lds16(gA + ((size_t)(tileMrow + r) * 2048) + kt * 64 + cb, sm + buf * 8192 + c * 1024);
    gload_lds16(gB + ((size_t)(tileNrow + r) * 2048) + kt * 64 + cb, sm + 16384 + buf * 8192 + c * 1024);
  }
}

DEV void gemm_main(const us* A, const us* Bw,
                   int tileMrow, int tileNrow, f32x4 acc[4][4], char* sm) {
  int tid = threadIdx.x, lane = tid & 63, wid = tid >> 6;
  int wr = wid >> 1, wc = wid & 1;
  gemm_stage(sm, A, Bw, tileMrow, tileNrow, 0, 0, lane, wid);
  for (int kt = 0; kt < 32; ++kt) {
    __syncthreads();
    if (kt < 31) gemm_stage(sm, A, Bw, tileMrow, tileNrow, (kt + 1) & 1, kt + 1, lane, wid);
    int ab = (kt & 1) * 8192;
    int rb = (lane & 15) * 64 + ((lane >> 4) * 16);
    short8 af[4], bf[4];
#pragma unroll
    for (int mi = 0; mi < 4; ++mi)
      af[mi] = *(const short8*)(sm + ab + (wr * 64 + mi * 16) * 64 + rb);
#pragma unroll
    for (int ni = 0; ni < 4; ++ni)
      bf[ni] = *(const short8*)(sm + 16384 + ab + (wc * 64 + ni * 16) * 64 + rb);
#pragma unroll
    for (int mi = 0; mi < 4; ++mi)
#pragma unroll
      for (int ni = 0; ni < 4; ++ni)
        acc[mi][ni] = MFMA16(af[mi], bf[ni], acc[mi][ni]);
  }
}

// ---------------- kernel 2: QKV+gate projection ----------------
__global__ __launch_bounds__(256) void gemm_qkvg_k(
    const us* __restrict__ Xbf, const us* __restrict__ Wbf,
    us* __restrict__ Qb, us* __restrict__ Kb, us* __restrict__ Vt,
    float* __restrict__ G, const float* __restrict__ bg) {
  __shared__ char sm[32768];
  int bid = blockIdx.x;
  int swz = (bid & 7) * 64 + (bid >> 3);
  int tileM = swz >> 5, tileN = swz & 31;
  f32x4 acc[4][4] = {};
  gemm_main(Xbf, Wbf, tileM * 128, tileN * 128, acc, sm);
  int lane = threadIdx.x & 63, wid = threadIdx.x >> 6;
  int wr = wid >> 1, wc = wid & 1;
#pragma unroll
  for (int mi = 0; mi < 4; ++mi)
#pragma unroll
    for (int ni = 0; ni < 4; ++ni)
#pragma unroll
      for (int j = 0; j < 4; ++j) {
        int row = tileM * 128 + wr * 64 + mi * 16 + ((lane >> 4) << 2) + j;
        int col = tileN * 128 + wc * 64 + ni * 16 + (lane & 15);
        float v = acc[mi][ni][j];
        int b = row >> 10, l = row & 1023;
        if (col < 3072) {
          int h = col / 192, r = col - h * 192;
          size_t base = ((size_t)(b * 16 + h) * 1024 + l) * 64;
          if (r < 64)        Qb[base + r] = f2b(v * 0.125f);
          else if (r < 128)  Kb[base + (r - 64)] = f2b(v);
          else               Vt[((size_t)(b * 16 + h) * 64 + (r - 128)) * 1024 + l] = f2b(v);
        } else {
          int e = col - 3072;
          float s = v + bg[e];
          G[(size_t)row * 1024 + e] = 1.f / (1.f + __expf(-s));
        }
      }
}

// ---------------- kernel 3: attention S-pass ----------------
// Block: (b, 16 q-rows, 256-lk chunk), ALL 16 heads. 4 waves; wave w owns
// heads 4w..4w+3. No max-subtraction (logits ~N(0,1.4); exp safe in f32).
__global__ __launch_bounds__(256) void attnS_k(
    const us* __restrict__ Qb, const us* __restrict__ Kb,
    const us* __restrict__ Vt, const float* __restrict__ bias,
    us* __restrict__ E, float* __restrict__ lpart, float* __restrict__ opart) {
  __shared__ float bt[8704];     // [16 q][32 lk][17 (16h + pad)]
  __shared__ char ps[20736];     // [16 h](stride 1296B) [16 q](80B) [32 lk] bf16
  int tid = threadIdx.x, lane = tid & 63, w = tid >> 6;
  int la = lane & 15, lg = lane >> 4;
  int bid = blockIdx.x;
  int kc = bid & 3, qt = (bid >> 2) & 63, b = bid >> 8;
  int lq0 = qt * 16, lk00 = kc * 256;

  short8 qf[4][2];
#pragma unroll
  for (int t = 0; t < 4; ++t) {
    int bh = b * 16 + w * 4 + t;
#pragma unroll
    for (int ks = 0; ks < 2; ++ks)
      qf[t][ks] = *(const short8*)(Qb + (size_t)bh * 65536 + (size_t)(lq0 + la) * 64 + ks * 32 + lg * 8);
  }

  f32x4 oacc[4][4] = {};
  float lacc[4][4] = {};

#pragma unroll 1
  for (int sc = 0; sc < 8; ++sc) {
    int lkg = lk00 + sc * 32;
    // ---- stage bias tile (coalesced f32x4 loads, every byte used) ----
#pragma unroll
    for (int i = 0; i < 8; ++i) {
      int f = i * 256 + tid;                 // f32x4 index in [16q][32lk][4 h4]
      int h4 = f & 3, lk = (f >> 2) & 31, q = f >> 7;
      f32x4 v = *(const f32x4*)(bias + ((size_t)b << 24) + ((size_t)(lq0 + q) << 14) +
                                ((size_t)(lkg + lk) << 4) + h4 * 4);
      int base = (q * 32 + lk) * 17 + h4 * 4;
      bt[base + 0] = v.x; bt[base + 1] = v.y; bt[base + 2] = v.z; bt[base + 3] = v.w;
    }
    __syncthreads();
    // ---- QK^T + bias(C-init) + exp + stash E ----
#pragma unroll
    for (int t = 0; t < 4; ++t) {
      int h = w * 4 + t;
      const us* Kh = Kb + (size_t)(b * 16 + h) * 65536;
#pragma unroll
      for (int fr = 0; fr < 2; ++fr) {
        const us* kr = Kh + (size_t)(lkg + fr * 16 + la) * 64 + lg * 8;
        short8 kf0 = *(const short8*)kr;
        short8 kf1 = *(const short8*)(kr + 32);
        f32x4 a;
#pragma unroll
        for (int j = 0; j < 4; ++j)
          a[j] = bt[((lg * 4 + j) * 32 + fr * 16 + la) * 17 + h];
        a = MFMA16(qf[t][0], kf0, a);
        a = MFMA16(qf[t][1], kf1, a);
#pragma unroll
        for (int j = 0; j < 4; ++j) {
          float e = __expf(a[j]);
          lacc[t][j] += e;
          *(us*)(ps + h * 1296 + (lg * 4 + j) * 80 + (fr * 16 + la) * 2) = f2b(e);
        }
      }
    }
    // ---- PV partial (own heads only; within-wave LDS RAW, no barrier) ----
#pragma unroll
    for (int t = 0; t < 4; ++t) {
      int h = w * 4 + t;
      short8 paf = *(const short8*)(ps + h * 1296 + la * 80 + lg * 16);
      const us* Vh = Vt + (size_t)(b * 16 + h) * 65536;
#pragma unroll
      for (int ni = 0; ni < 4; ++ni) {
        short8 vf = *(const short8*)(Vh + (size_t)(ni * 16 + la) * 1024 + lkg + lg * 8);
        oacc[t][ni] = MFMA16(paf, vf, oacc[t][ni]);
      }
    }
    __syncthreads();
    // ---- E out-copy: [lk][h][16 q] coalesced bf16 stores ----
#pragma unroll
    for (int i = 0; i < 2; ++i) {
      int p = i * 256 + tid;
      int hh = p & 15, lkl = p >> 4;
      const char* pr = ps + hh * 1296 + lkl * 2;
      short8 s0, s1;
#pragma unroll
      for (int q = 0; q < 8; ++q) s0[q] = (short)*(const us*)(pr + q * 80);
#pragma unroll
      for (int q = 0; q < 8; ++q) s1[q] = (short)*(const us*)(pr + (q + 8) * 80);
      us* dst = E + ((size_t)b << 24) + ((size_t)(lkg + lkl) << 14) + (hh << 10) + lq0;
      *(short8*)dst = s0;
      *(short8*)(dst + 8) = s1;
    }
  }

  // ---- epilogue: l partials (reduce over la) + O partials ----
#pragma unroll
  for (int d = 1; d < 16; d <<= 1)
#pragma unroll
    for (int t = 0; t < 4; ++t)
#pragma unroll
      for (int j = 0; j < 4; ++j) lacc[t][j] += __shfl_xor(lacc[t][j], d);
  if (la == 0) {
#pragma unroll
    for (int t = 0; t < 4; ++t)
#pragma unroll
      for (int j = 0; j < 4; ++j)
        lpart[kc * 32768 + (b * 16 + w * 4 + t) * 1024 + lq0 + lg * 4 + j] = lacc[t][j];
  }
#pragma unroll
  for (int t = 0; t < 4; ++t)
#pragma unroll
    for (int ni = 0; ni < 4; ++ni)
#pragma unroll
      for (int j = 0; j < 4; ++j)
        opart[(size_t)kc * 2097152 +
              ((size_t)(b * 16 + w * 4 + t) * 1024 + lq0 + lg * 4 + j) * 64 + ni * 16 + la] =
            oacc[t][ni][j];
}

// ---------------- kernel 4: l merge -> 1/l ----------------
__global__ __launch_bounds__(256) void linv_k(const float* __restrict__ lpart,
                                              float* __restrict__ linv) {
  int idx = blockIdx.x * 256 + threadIdx.x;  // 32768
  float s = lpart[idx] + lpart[32768 + idx] + lpart[65536 + idx] + lpart[98304 + idx];
  linv[idx] = 1.f / s;
}

// ---------------- kernel 5: normalize E -> probs fp32 ; O merge * linv * gate -> Y ----
__global__ __launch_bounds__(256) void norm_k(
    const us* __restrict__ E, const float* __restrict__ linv,
    const float* __restrict__ opart, const float* __restrict__ G,
    float* __restrict__ outa, us* __restrict__ Ybf) {
  int bid = blockIdx.x, tid = threadIdx.x;
  if (bid < 2048) {
#pragma unroll
    for (int k = 0; k < 8; ++k) {
      int u = bid * 256 + tid + k * 524288;
      int row = u >> 7, lq8 = (u & 127) * 8;   // row = (b*1024+lk)*16+h
      short8 ev = *(const short8*)(E + ((size_t)row << 10) + lq8);
      const float* lv = linv + ((row >> 14) << 14) + ((row & 15) << 10) + lq8;
      f32x4 l0 = *(const f32x4*)lv, l1 = *(const f32x4*)(lv + 4);
      f32x4 o0, o1;
#pragma unroll
      for (int i = 0; i < 4; ++i) {
        o0[i] = b2f((us)ev[i]) * l0[i];
        o1[i] = b2f((us)ev[4 + i]) * l1[i];
      }
      float* dst = outa + ((size_t)row << 10) + lq8;
      *(f32x4*)dst = o0;
      *(f32x4*)(dst + 4) = o1;
    }
  } else {
    int bidp = bid - 2048;
#pragma unroll
    for (int k = 0; k < 16; ++k) {
      int u = bidp * 256 + tid + k * 32768;
      size_t off = (size_t)u * 4;              // [b][h][q][c] flat
      f32x4 o = *(const f32x4*)(opart + off);
#pragma unroll
      for (int kc = 1; kc < 4; ++kc) {
        f32x4 p = *(const f32x4*)(opart + (size_t)kc * 2097152 + off);
        o.x += p.x; o.y += p.y; o.z += p.z; o.w += p.w;
      }
      float li = linv[off >> 6];               // row (b*16+h)*1024+q
      int b = (int)(off >> 20), h = (int)((off >> 16) & 15);
      int q = (int)((off >> 6) & 1023), c = (int)(off & 63);
      size_t gidx = (((size_t)b * 1024 + q) << 10) + h * 64 + c;
      f32x4 g = *(const f32x4*)(G + gidx);
      u16x4 y;
      y.x = f2b(o.x * li * g.x); y.y = f2b(o.y * li * g.y);
      y.z = f2b(o.z * li * g.z); y.w = f2b(o.w * li * g.w);
      *(u16x4*)(Ybf + gidx) = y;
    }
  }
}

// ---------------- kernel 6: output projection ----------------
__global__ __launch_bounds__(256) void gemm_out_k(
    const us* __restrict__ Ybf, const us* __restrict__ Wobf,
    const float* __restrict__ bo, float* __restrict__ outy) {
  __shared__ char sm[32768];
  int bid = blockIdx.x;
  int swz = (bid & 7) * 16 + (bid >> 3);
  int tileM = swz >> 3, tileN = swz & 7;
  f32x4 acc[4][4] = {};
  gemm_main(Ybf, Wobf, tileM * 128, tileN * 128, acc, sm);
  int lane = threadIdx.x & 63, wid = threadIdx.x >> 6;
  int wr = wid >> 1, wc = wid & 1;
#pragma unroll
  for (int mi = 0; mi < 4; ++mi)
#pragma unroll
    for (int ni = 0; ni < 4; ++ni)
#pragma unroll
      for (int j = 0; j < 4; ++j) {
        int row = tileM * 128 + wr * 64 + mi * 16 + ((lane >> 4) << 2) + j;
        int col = tileN * 128 + wc * 64 + ni * 16 + (lane & 15);
        outy[(size_t)row * 1024 + col] = acc[mi][ni][j] + bo[col];
      }
}

extern "C" void kernel_launch(void* const* d_in, const int* in_sizes, int n_in,
                              void* d_out, int out_size, void* d_ws, size_t ws_size,
                              hipStream_t stream) {
  const float* x     = (const float*)d_in[0];
  const float* bias  = (const float*)d_in[1];
  const float* wproj = (const float*)d_in[2];
  const float* wo    = (const float*)d_in[3];
  const float* bo    = (const float*)d_in[4];
  const float* wg    = (const float*)d_in[5];
  const float* bg    = (const float*)d_in[6];
  float* outy = (float*)d_out;
  float* outa = outy + 2097152;  // y (2M f32), then probs (B,Lk,H,Lq) f32

  char* ws = (char*)d_ws;
  us*    Xbf  = (us*)(ws);
  us*    Wbf  = (us*)(ws + 4  * 1024 * 1024);
  us*    Wobf = (us*)(ws + 12 * 1024 * 1024);
  us*    Qb   = (us*)(ws + 14 * 1024 * 1024);
  us*    Kb   = (us*)(ws + 18 * 1024 * 1024);
  us*    Vt   = (us*)(ws + 22 * 1024 * 1024);
  float* G    = (float*)(ws + 26 * 1024 * 1024);
  us*    Ybf  = (us*)(ws + 34 * 1024 * 1024);
  float* lpart= (float*)(ws + (size_t)38 * 1024 * 1024);   // 512 KB
  float* linv = (float*)(ws + (size_t)39 * 1024 * 1024);   // 128 KB
  float* opart= (float*)(ws + (size_t)40 * 1024 * 1024);   // 32 MB
  us*    E    = (us*)   (ws + (size_t)72 * 1024 * 1024);   // 64 MB
  if (ws_size < (size_t)137 * 1024 * 1024) return;

  prep_k<<<dim3(7168), dim3(256), 0, stream>>>(x, wproj, wg, wo, Xbf, Wbf, Wobf);
  gemm_qkvg_k<<<dim3(512), dim3(256), 0, stream>>>(Xbf, Wbf, Qb, Kb, Vt, G, bg);
  attnS_k<<<dim3(512), dim3(256), 0, stream>>>(Qb, Kb, Vt, bias, E, lpart, opart);
  linv_k<<<dim3(128), dim3(256), 0, stream>>>(lpart, linv);
  norm_k<<<dim3(2176), dim3(256), 0, stream>>>(E, linv, opart, G, outa, Ybf);
  gemm_out_k<<<dim3(128), dim3(256), 0, stream>>>(Ybf, Wobf, bo, outy);
}

// Round 6
// 209.671 us; speedup vs baseline: 1.2666x; 1.2666x over previous
//
#include <hip/hip_runtime.h>
#include <hip/hip_bf16.h>
#include <stdint.h>

typedef __attribute__((ext_vector_type(4))) float f32x4;
typedef __attribute__((ext_vector_type(8))) short short8;
typedef __attribute__((ext_vector_type(4))) unsigned short u16x4;
typedef unsigned short us;

#define DEV __device__ __forceinline__
#define MFMA16(a, b, c) __builtin_amdgcn_mfma_f32_16x16x32_bf16(a, b, c, 0, 0, 0)

DEV us f2b(float x) {
  union { float f; uint32_t u; } c; c.f = x;
  uint32_t r = (c.u + 0x7fffu + ((c.u >> 16) & 1u)) >> 16;
  return (us)r;
}
DEV float b2f(us x) {
  union { uint32_t u; float f; } c; c.u = ((uint32_t)x) << 16;
  return c.f;
}
DEV us f2h(float x) { union { _Float16 h; us u; } c; c.h = (_Float16)x; return c.u; }
DEV float h2f(us x) { union { us u; _Float16 h; } c; c.u = x; return (float)c.h; }

DEV void gload_lds16(const void* g, void* l) {
  __builtin_amdgcn_global_load_lds((const __attribute__((address_space(1))) void*)g,
                                   (__attribute__((address_space(3))) void*)l, 16, 0, 0);
}

// ---------------- kernel 1: fp32 -> bf16 conversions ----------------
__global__ __launch_bounds__(256) void prep_k(
    const float* __restrict__ x, const float* __restrict__ wproj,
    const float* __restrict__ wg, const float* __restrict__ wo,
    us* __restrict__ Xbf, us* __restrict__ Wbf, us* __restrict__ Wobf) {
  int i = blockIdx.x * 256 + threadIdx.x;
  const float* src; us* dst;
  if (i < 524288)               { src = x     + (size_t)i * 4;                  dst = Xbf + (size_t)i * 4; }
  else if (i < 524288 + 786432) { int j = i - 524288;            src = wproj + (size_t)j * 4; dst = Wbf + (size_t)j * 4; }
  else if (i < 524288 + 786432 + 262144) { int j = i - (524288 + 786432); src = wg + (size_t)j * 4; dst = Wbf + 3145728 + (size_t)j * 4; }
  else                          { int j = i - (524288 + 786432 + 262144); src = wo + (size_t)j * 4; dst = Wobf + (size_t)j * 4; }
  f32x4 v = *(const f32x4*)src;
  u16x4 o; o.x = f2b(v.x); o.y = f2b(v.y); o.z = f2b(v.z); o.w = f2b(v.w);
  *(u16x4*)dst = o;
}

// ---------------- shared GEMM core (m97-style, 128x128) ----------------
DEV void gemm_stage(char* sm, const us* A, const us* Bw,
                    int tileMrow, int tileNrow, int buf, int kt, int lane, int wid) {
  const char* gA = (const char*)A;
  const char* gB = (const char*)Bw;
#pragma unroll
  for (int i = 0; i < 2; ++i) {
    int c = wid * 2 + i;
    int off = c * 1024 + lane * 16;
    int r = off >> 6, cb = off & 63;
    gload_lds16(gA + ((size_t)(tileMrow + r) * 2048) + kt * 64 + cb, sm + buf * 8192 + c * 1024);
    gload_lds16(gB + ((size_t)(tileNrow + r) * 2048) + kt * 64 + cb, sm + 16384 + buf * 8192 + c * 1024);
  }
}

DEV void gemm_main(const us* A, const us* Bw,
                   int tileMrow, int tileNrow, f32x4 acc[4][4], char* sm) {
  int tid = threadIdx.x, lane = tid & 63, wid = tid >> 6;
  int wr = wid >> 1, wc = wid & 1;
  gemm_stage(sm, A, Bw, tileMrow, tileNrow, 0, 0, lane, wid);
  for (int kt = 0; kt < 32; ++kt) {
    __syncthreads();
    if (kt < 31) gemm_stage(sm, A, Bw, tileMrow, tileNrow, (kt + 1) & 1, kt + 1, lane, wid);
    int ab = (kt & 1) * 8192;
    int rb = (lane & 15) * 64 + ((lane >> 4) * 16);
    short8 af[4], bf[4];
#pragma unroll
    for (int mi = 0; mi < 4; ++mi)
      af[mi] = *(const short8*)(sm + ab + (wr * 64 + mi * 16) * 64 + rb);
#pragma unroll
    for (int ni = 0; ni < 4; ++ni)
      bf[ni] = *(const short8*)(sm + 16384 + ab + (wc * 64 + ni * 16) * 64 + rb);
#pragma unroll
    for (int mi = 0; mi < 4; ++mi)
#pragma unroll
      for (int ni = 0; ni < 4; ++ni)
        acc[mi][ni] = MFMA16(af[mi], bf[ni], acc[mi][ni]);
  }
}

// ---------------- kernel 2: QKV+gate projection ----------------
__global__ __launch_bounds__(256) void gemm_qkvg_k(
    const us* __restrict__ Xbf, const us* __restrict__ Wbf,
    us* __restrict__ Qb, us* __restrict__ Kb, us* __restrict__ Vt,
    float* __restrict__ G, const float* __restrict__ bg) {
  __shared__ char sm[32768];
  int bid = blockIdx.x;
  int swz = (bid & 7) * 64 + (bid >> 3);
  int tileM = swz >> 5, tileN = swz & 31;
  f32x4 acc[4][4] = {};
  gemm_main(Xbf, Wbf, tileM * 128, tileN * 128, acc, sm);
  int lane = threadIdx.x & 63, wid = threadIdx.x >> 6;
  int wr = wid >> 1, wc = wid & 1;
#pragma unroll
  for (int mi = 0; mi < 4; ++mi)
#pragma unroll
    for (int ni = 0; ni < 4; ++ni)
#pragma unroll
      for (int j = 0; j < 4; ++j) {
        int row = tileM * 128 + wr * 64 + mi * 16 + ((lane >> 4) << 2) + j;
        int col = tileN * 128 + wc * 64 + ni * 16 + (lane & 15);
        float v = acc[mi][ni][j];
        int b = row >> 10, l = row & 1023;
        if (col < 3072) {
          int h = col / 192, r = col - h * 192;
          size_t base = ((size_t)(b * 16 + h) * 1024 + l) * 64;
          if (r < 64)        Qb[base + r] = f2b(v * 0.125f);
          else if (r < 128)  Kb[base + (r - 64)] = f2b(v);
          else               Vt[((size_t)(b * 16 + h) * 64 + (r - 128)) * 1024 + l] = f2b(v);
        } else {
          int e = col - 3072;
          float s = v + bg[e];
          G[(size_t)row * 1024 + e] = 1.f / (1.f + __expf(-s));
        }
      }
}

// ---------------- kernel 3: S = QK^T -> fp16, layout (B,Lq,H,Lk) ----------------
// Swapped MFMA operands: lane holds contiguous lk-runs -> vectorized 8B stores.
// Grid 1024: bid = g*256 + qt*8 + xx; bh = g*8+xx (32 q-blocks of a bh share an XCD).
__global__ __launch_bounds__(256) void qk_k(
    const us* __restrict__ Qb, const us* __restrict__ Kb, us* __restrict__ SE) {
  int tid = threadIdx.x, lane = tid & 63, w = tid >> 6;
  int la = lane & 15, lg = lane >> 4;
  int bid = blockIdx.x;
  int g = bid >> 8, qt = (bid >> 3) & 31, xx = bid & 7;
  int bh = g * 8 + xx;
  int b = bh >> 4, h = bh & 15;
  int qb = qt * 32;
  const us* Qh = Qb + (size_t)bh * 65536;
  const us* Kh = Kb + (size_t)bh * 65536;
  int lk0 = w * 256;

  short8 qf[2][2];
#pragma unroll
  for (int qh = 0; qh < 2; ++qh)
#pragma unroll
    for (int ks = 0; ks < 2; ++ks)
      qf[qh][ks] = *(const short8*)(Qh + (size_t)(qb + qh * 16 + la) * 64 + ks * 32 + lg * 8);

  f32x4 acc[2][16] = {};
#pragma unroll
  for (int nf = 0; nf < 16; ++nf) {
    const us* kr = Kh + (size_t)(lk0 + nf * 16 + la) * 64 + lg * 8;
    short8 kf0 = *(const short8*)kr;
    short8 kf1 = *(const short8*)(kr + 32);
    acc[0][nf] = MFMA16(kf0, qf[0][0], acc[0][nf]);
    acc[0][nf] = MFMA16(kf1, qf[0][1], acc[0][nf]);
    acc[1][nf] = MFMA16(kf0, qf[1][0], acc[1][nf]);
    acc[1][nf] = MFMA16(kf1, qf[1][1], acc[1][nf]);
  }
  // D mapping (swapped): col(la) = q-local, row(lg*4+j) = lk-local
#pragma unroll
  for (int qh = 0; qh < 2; ++qh)
#pragma unroll
    for (int nf = 0; nf < 16; ++nf) {
      u16x4 o;
#pragma unroll
      for (int j = 0; j < 4; ++j) o[j] = f2h(acc[qh][nf][j]);
      *(u16x4*)(SE + (((size_t)(b * 1024 + qb + qh * 16 + la) * 16 + h) << 10) +
                lk0 + nf * 16 + lg * 4) = o;
    }
}

// ---------------- kernel 4: E = exp(S + bias) in-place, lsum -> linv ----------------
// Block (b, lq): all 16 h x all 1024 lk. Bias staged coalesced -> LDS [256][17].
__global__ __launch_bounds__(256) void exp_k(
    us* __restrict__ SE, const float* __restrict__ bias, float* __restrict__ linv) {
  __shared__ float bt[4352];  // [256 lk][17]
  int tid = threadIdx.x;
  int la = tid & 15, h = tid >> 4;  // h = 4*w + lg
  int bid = blockIdx.x;
  int lq = bid & 1023, b = bid >> 10;
  const float* brow = bias + ((size_t)b << 24) + ((size_t)lq << 14);
  us* row = SE + (((size_t)(b * 1024 + lq) * 16 + h) << 10);
  float lsum = 0.f;

#pragma unroll 1
  for (int ch = 0; ch < 4; ++ch) {
    int lk0 = ch * 256;
    __syncthreads();  // previous chunk's bt reads done
#pragma unroll
    for (int i = 0; i < 4; ++i) {
      int f = i * 256 + tid;             // f32x4 index in [256 lk][4 h4]
      int lk = f >> 2, h4 = f & 3;
      f32x4 v = *(const f32x4*)(brow + (size_t)(lk0 + lk) * 16 + h4 * 4);
      int base = lk * 17 + h4 * 4;
      bt[base] = v.x; bt[base + 1] = v.y; bt[base + 2] = v.z; bt[base + 3] = v.w;
    }
    __syncthreads();
#pragma unroll
    for (int j = 0; j < 4; ++j) {
      int lkl = 4 * (la + 16 * j);
      u16x4 sv = *(const u16x4*)(row + lk0 + lkl);
      u16x4 ev;
#pragma unroll
      for (int i = 0; i < 4; ++i) {
        float e = __expf(h2f(sv[i]) + bt[(lkl + i) * 17 + h]);
        lsum += e;
        ev[i] = f2b(e);
      }
      *(u16x4*)(row + lk0 + lkl) = ev;
    }
  }
#pragma unroll
  for (int d = 1; d < 16; d <<= 1) lsum += __shfl_xor(lsum, d);
  if (la == 0) linv[((size_t)(b * 16 + h) << 10) + lq] = 1.f / lsum;
}

// ---------------- kernel 5: PV + transposed probs + gate ----------------
// Block (b,h,32q), 4 waves x 256 lk. E tile staged once into XOR-swizzled LDS,
// feeds both the probs transpose (coalesced f32x4 out) and PV MFMA A-frags.
__global__ __launch_bounds__(256) void pv_k(
    const us* __restrict__ E, const us* __restrict__ Vt,
    const float* __restrict__ linv, const float* __restrict__ G,
    float* __restrict__ outa, us* __restrict__ Ybf) {
  __shared__ char sm[49792];
  float* lv = (float*)(sm + 49664);
  int tid = threadIdx.x, lane = tid & 63, w = tid >> 6;
  int la = lane & 15, lg = lane >> 4;
  int bid = blockIdx.x;
  int g = bid >> 8, qt = (bid >> 3) & 31, xx = bid & 7;
  int bh = g * 8 + xx;
  int b = bh >> 4, h = bh & 15;
  int qb = qt * 32;
  if (tid < 32) lv[tid] = linv[((size_t)bh << 10) + qb + tid];
  __syncthreads();
  char* pb = sm + w * 4096;  // [32 q][64 lk] bf16, chunk-XOR swizzle
  const us* Vh = Vt + (size_t)bh * 65536;
  f32x4 yacc[2][4] = {};
  int lkw = w * 256;

#pragma unroll 1
  for (int cc = 0; cc < 4; ++cc) {
    int lk0 = lkw + cc * 64;
    // stage E tile (reg-staged so dest can be swizzled)
#pragma unroll
    for (int it = 0; it < 4; ++it) {
      int ci = it * 64 + lane;
      int q = ci >> 3, c16 = ci & 7;
      short8 ev = *(const short8*)(E + (((size_t)(b * 1024 + qb + q) * 16 + h) << 10) + lk0 + c16 * 8);
      *(short8*)(pb + q * 128 + ((c16 * 16) ^ ((q & 7) << 4))) = ev;
    }
    // transposed probs: outa[b][lk][h][qb..qb+32)
#pragma unroll
    for (int it = 0; it < 8; ++it) {
      int idx = it * 64 + lane;
      int lkL = idx >> 3, q4 = idx & 7;
      f32x4 ov;
#pragma unroll
      for (int i = 0; i < 4; ++i) {
        int q = q4 * 4 + i;
        us e = *(const us*)(pb + q * 128 + ((2 * lkL) ^ ((q & 7) << 4)));
        ov[i] = b2f(e) * lv[q];
      }
      *(f32x4*)(outa + (((size_t)(b * 1024 + lk0 + lkL) * 16 + h) << 10) + qb + q4 * 4) = ov;
    }
    // PV
#pragma unroll
    for (int ks = 0; ks < 2; ++ks) {
      short8 pa[2];
#pragma unroll
      for (int qh = 0; qh < 2; ++qh) {
        int row = qh * 16 + la;
        pa[qh] = *(const short8*)(pb + row * 128 + ((ks * 64 + lg * 16) ^ ((row & 7) << 4)));
      }
#pragma unroll
      for (int ni = 0; ni < 4; ++ni) {
        short8 vf = *(const short8*)(Vh + (size_t)(ni * 16 + la) * 1024 + lk0 + ks * 32 + lg * 8);
        yacc[0][ni] = MFMA16(pa[0], vf, yacc[0][ni]);
        yacc[1][ni] = MFMA16(pa[1], vf, yacc[1][ni]);
      }
    }
  }

  // cross-wave O reduce + linv + gate
  float* red = (float*)(sm + 16384);  // [4 w][32 r][65]
#pragma unroll
  for (int qh = 0; qh < 2; ++qh)
#pragma unroll
    for (int ni = 0; ni < 4; ++ni)
#pragma unroll
      for (int j = 0; j < 4; ++j) {
        int r = qh * 16 + lg * 4 + j, c = ni * 16 + la;
        red[w * 2080 + r * 65 + c] = yacc[qh][ni][j];
      }
  __syncthreads();
#pragma unroll
  for (int rr = 0; rr < 8; ++rr) {
    int e = rr * 256 + tid;
    int r = e >> 6, c = e & 63;
    float s = red[r * 65 + c] + red[2080 + r * 65 + c] +
              red[4160 + r * 65 + c] + red[6240 + r * 65 + c];
    size_t gi = (((size_t)(b * 1024 + qb + r)) << 10) + h * 64 + c;
    Ybf[gi] = f2b(s * lv[r] * G[gi]);
  }
}

// ---------------- kernel 6: output projection ----------------
__global__ __launch_bounds__(256) void gemm_out_k(
    const us* __restrict__ Ybf, const us* __restrict__ Wobf,
    const float* __restrict__ bo, float* __restrict__ outy) {
  __shared__ char sm[32768];
  int bid = blockIdx.x;
  int swz = (bid & 7) * 16 + (bid >> 3);
  int tileM = swz >> 3, tileN = swz & 7;
  f32x4 acc[4][4] = {};
  gemm_main(Ybf, Wobf, tileM * 128, tileN * 128, acc, sm);
  int lane = threadIdx.x & 63, wid = threadIdx.x >> 6;
  int wr = wid >> 1, wc = wid & 1;
#pragma unroll
  for (int mi = 0; mi < 4; ++mi)
#pragma unroll
    for (int ni = 0; ni < 4; ++ni)
#pragma unroll
      for (int j = 0; j < 4; ++j) {
        int row = tileM * 128 + wr * 64 + mi * 16 + ((lane >> 4) << 2) + j;
        int col = tileN * 128 + wc * 64 + ni * 16 + (lane & 15);
        outy[(size_t)row * 1024 + col] = acc[mi][ni][j] + bo[col];
      }
}

extern "C" void kernel_launch(void* const* d_in, const int* in_sizes, int n_in,
                              void* d_out, int out_size, void* d_ws, size_t ws_size,
                              hipStream_t stream) {
  const float* x     = (const float*)d_in[0];
  const float* bias  = (const float*)d_in[1];
  const float* wproj = (const float*)d_in[2];
  const float* wo    = (const float*)d_in[3];
  const float* bo    = (const float*)d_in[4];
  const float* wg    = (const float*)d_in[5];
  const float* bg    = (const float*)d_in[6];
  float* outy = (float*)d_out;
  float* outa = outy + 2097152;  // y (2M f32), then probs (B,Lk,H,Lq) f32

  char* ws = (char*)d_ws;
  us*    Xbf  = (us*)(ws);
  us*    Wbf  = (us*)(ws + 4  * 1024 * 1024);
  us*    Wobf = (us*)(ws + 12 * 1024 * 1024);
  us*    Qb   = (us*)(ws + 14 * 1024 * 1024);
  us*    Kb   = (us*)(ws + 18 * 1024 * 1024);
  us*    Vt   = (us*)(ws + 22 * 1024 * 1024);
  float* G    = (float*)(ws + 26 * 1024 * 1024);
  us*    Ybf  = (us*)(ws + 34 * 1024 * 1024);
  us*    SE   = (us*)(ws + (size_t)38 * 1024 * 1024);   // 64 MB: S fp16 -> E bf16 in-place
  float* linv = (float*)(ws + (size_t)102 * 1024 * 1024); // 128 KB
  if (ws_size < (size_t)103 * 1024 * 1024) return;

  prep_k<<<dim3(7168), dim3(256), 0, stream>>>(x, wproj, wg, wo, Xbf, Wbf, Wobf);
  gemm_qkvg_k<<<dim3(512), dim3(256), 0, stream>>>(Xbf, Wbf, Qb, Kb, Vt, G, bg);
  qk_k<<<dim3(1024), dim3(256), 0, stream>>>(Qb, Kb, SE);
  exp_k<<<dim3(2048), dim3(256), 0, stream>>>(SE, bias, linv);
  pv_k<<<dim3(1024), dim3(256), 0, stream>>>(SE, Vt, linv, G, outa, Ybf);
  gemm_out_k<<<dim3(128), dim3(256), 0, stream>>>(Ybf, Wobf, bo, outy);
}

// Round 7
// 207.227 us; speedup vs baseline: 1.2815x; 1.0118x over previous
//
#include <hip/hip_runtime.h>
#include <hip/hip_bf16.h>
#include <stdint.h>

typedef __attribute__((ext_vector_type(4))) float f32x4;
typedef __attribute__((ext_vector_type(8))) short short8;
typedef __attribute__((ext_vector_type(4))) unsigned short u16x4;
typedef unsigned short us;

#define DEV __device__ __forceinline__
#define MFMA16(a, b, c) __builtin_amdgcn_mfma_f32_16x16x32_bf16(a, b, c, 0, 0, 0)

DEV us f2b(float x) {
  union { float f; uint32_t u; } c; c.f = x;
  uint32_t r = (c.u + 0x7fffu + ((c.u >> 16) & 1u)) >> 16;
  return (us)r;
}
DEV float b2f(us x) {
  union { uint32_t u; float f; } c; c.u = ((uint32_t)x) << 16;
  return c.f;
}
DEV us f2h(float x) { union { _Float16 h; us u; } c; c.h = (_Float16)x; return c.u; }
DEV float h2f(us x) { union { us u; _Float16 h; } c; c.u = x; return (float)c.h; }

DEV void gload_lds16(const void* g, void* l) {
  __builtin_amdgcn_global_load_lds((const __attribute__((address_space(1))) void*)g,
                                   (__attribute__((address_space(3))) void*)l, 16, 0, 0);
}

// ---------------- kernel 1: fp32 -> bf16 conversions ----------------
__global__ __launch_bounds__(256) void prep_k(
    const float* __restrict__ x, const float* __restrict__ wproj,
    const float* __restrict__ wg, const float* __restrict__ wo,
    us* __restrict__ Xbf, us* __restrict__ Wbf, us* __restrict__ Wobf) {
  int i = blockIdx.x * 256 + threadIdx.x;
  const float* src; us* dst;
  if (i < 524288)               { src = x     + (size_t)i * 4;                  dst = Xbf + (size_t)i * 4; }
  else if (i < 524288 + 786432) { int j = i - 524288;            src = wproj + (size_t)j * 4; dst = Wbf + (size_t)j * 4; }
  else if (i < 524288 + 786432 + 262144) { int j = i - (524288 + 786432); src = wg + (size_t)j * 4; dst = Wbf + 3145728 + (size_t)j * 4; }
  else                          { int j = i - (524288 + 786432 + 262144); src = wo + (size_t)j * 4; dst = Wobf + (size_t)j * 4; }
  f32x4 v = *(const f32x4*)src;
  u16x4 o; o.x = f2b(v.x); o.y = f2b(v.y); o.z = f2b(v.z); o.w = f2b(v.w);
  *(u16x4*)dst = o;
}

// ---------------- shared GEMM core (m97-style, 128x128) ----------------
DEV void gemm_stage(char* sm, const us* A, const us* Bw,
                    int tileMrow, int tileNrow, int buf, int kt, int lane, int wid) {
  const char* gA = (const char*)A;
  const char* gB = (const char*)Bw;
#pragma unroll
  for (int i = 0; i < 2; ++i) {
    int c = wid * 2 + i;
    int off = c * 1024 + lane * 16;
    int r = off >> 6, cb = off & 63;
    gload_lds16(gA + ((size_t)(tileMrow + r) * 2048) + kt * 64 + cb, sm + buf * 8192 + c * 1024);
    gload_lds16(gB + ((size_t)(tileNrow + r) * 2048) + kt * 64 + cb, sm + 16384 + buf * 8192 + c * 1024);
  }
}

DEV void gemm_main(const us* A, const us* Bw,
                   int tileMrow, int tileNrow, f32x4 acc[4][4], char* sm) {
  int tid = threadIdx.x, lane = tid & 63, wid = tid >> 6;
  int wr = wid >> 1, wc = wid & 1;
  gemm_stage(sm, A, Bw, tileMrow, tileNrow, 0, 0, lane, wid);
  for (int kt = 0; kt < 32; ++kt) {
    __syncthreads();
    if (kt < 31) gemm_stage(sm, A, Bw, tileMrow, tileNrow, (kt + 1) & 1, kt + 1, lane, wid);
    int ab = (kt & 1) * 8192;
    int rb = (lane & 15) * 64 + ((lane >> 4) * 16);
    short8 af[4], bf[4];
#pragma unroll
    for (int mi = 0; mi < 4; ++mi)
      af[mi] = *(const short8*)(sm + ab + (wr * 64 + mi * 16) * 64 + rb);
#pragma unroll
    for (int ni = 0; ni < 4; ++ni)
      bf[ni] = *(const short8*)(sm + 16384 + ab + (wc * 64 + ni * 16) * 64 + rb);
#pragma unroll
    for (int mi = 0; mi < 4; ++mi)
#pragma unroll
      for (int ni = 0; ni < 4; ++ni)
        acc[mi][ni] = MFMA16(af[mi], bf[ni], acc[mi][ni]);
  }
}

// ---------------- kernel 2: QKV+gate projection ----------------
__global__ __launch_bounds__(256) void gemm_qkvg_k(
    const us* __restrict__ Xbf, const us* __restrict__ Wbf,
    us* __restrict__ Qb, us* __restrict__ Kb, us* __restrict__ Vt,
    float* __restrict__ G, const float* __restrict__ bg) {
  __shared__ char sm[32768];
  int bid = blockIdx.x;
  int swz = (bid & 7) * 64 + (bid >> 3);
  int tileM = swz >> 5, tileN = swz & 31;
  f32x4 acc[4][4] = {};
  gemm_main(Xbf, Wbf, tileM * 128, tileN * 128, acc, sm);
  int lane = threadIdx.x & 63, wid = threadIdx.x >> 6;
  int wr = wid >> 1, wc = wid & 1;
#pragma unroll
  for (int mi = 0; mi < 4; ++mi)
#pragma unroll
    for (int ni = 0; ni < 4; ++ni)
#pragma unroll
      for (int j = 0; j < 4; ++j) {
        int row = tileM * 128 + wr * 64 + mi * 16 + ((lane >> 4) << 2) + j;
        int col = tileN * 128 + wc * 64 + ni * 16 + (lane & 15);
        float v = acc[mi][ni][j];
        int b = row >> 10, l = row & 1023;
        if (col < 3072) {
          int h = col / 192, r = col - h * 192;
          size_t base = ((size_t)(b * 16 + h) * 1024 + l) * 64;
          if (r < 64)        Qb[base + r] = f2b(v * 0.125f);
          else if (r < 128)  Kb[base + (r - 64)] = f2b(v);
          else               Vt[((size_t)(b * 16 + h) * 64 + (r - 128)) * 1024 + l] = f2b(v);
        } else {
          int e = col - 3072;
          float s = v + bg[e];
          G[(size_t)row * 1024 + e] = 1.f / (1.f + __expf(-s));
        }
      }
}

// ---------------- kernel 3: S = QK^T -> fp16, layout (B,Lq,H,Lk) ----------------
// Swapped MFMA operands (lane = q, reg = lk). Store via LDS restage so each
// global store writes full 64B lines: per qh-half, waves dump [16q][256lk]
// fragments into pad-264 LDS, then 256 threads copy 16 complete 2KB rows.
__global__ __launch_bounds__(256) void qk_k(
    const us* __restrict__ Qb, const us* __restrict__ Kb, us* __restrict__ SE) {
  __shared__ char sq[33792];  // 4 waves x [16 q][264 fp16] (528B row stride)
  int tid = threadIdx.x, lane = tid & 63, w = tid >> 6;
  int la = lane & 15, lg = lane >> 4;
  int bid = blockIdx.x;
  int g = bid >> 8, qt = (bid >> 3) & 31, xx = bid & 7;
  int bh = g * 8 + xx;
  int b = bh >> 4, h = bh & 15;
  int qb = qt * 32;
  const us* Qh = Qb + (size_t)bh * 65536;
  const us* Kh = Kb + (size_t)bh * 65536;
  int lk0 = w * 256;

  short8 qf[2][2];
#pragma unroll
  for (int qh = 0; qh < 2; ++qh)
#pragma unroll
    for (int ks = 0; ks < 2; ++ks)
      qf[qh][ks] = *(const short8*)(Qh + (size_t)(qb + qh * 16 + la) * 64 + ks * 32 + lg * 8);

  f32x4 acc[2][16] = {};
#pragma unroll
  for (int nf = 0; nf < 16; ++nf) {
    const us* kr = Kh + (size_t)(lk0 + nf * 16 + la) * 64 + lg * 8;
    short8 kf0 = *(const short8*)kr;
    short8 kf1 = *(const short8*)(kr + 32);
    acc[0][nf] = MFMA16(kf0, qf[0][0], acc[0][nf]);
    acc[0][nf] = MFMA16(kf1, qf[0][1], acc[0][nf]);
    acc[1][nf] = MFMA16(kf0, qf[1][0], acc[1][nf]);
    acc[1][nf] = MFMA16(kf1, qf[1][1], acc[1][nf]);
  }
  // D mapping (swapped): col(la) = q-local, row(lg*4+j) = lk-local
  char* myb = sq + w * 8448;
#pragma unroll
  for (int qh = 0; qh < 2; ++qh) {
    if (qh) __syncthreads();  // copy-out of prev half done before overwrite
#pragma unroll
    for (int nf = 0; nf < 16; ++nf) {
      u16x4 o;
#pragma unroll
      for (int j = 0; j < 4; ++j) o[j] = f2h(acc[qh][nf][j]);
      *(u16x4*)(myb + la * 528 + nf * 32 + lg * 8) = o;
    }
    __syncthreads();
    // coalesced copy-out: 16 rows x 1024 fp16 (2KB contiguous each)
#pragma unroll
    for (int it = 0; it < 8; ++it) {
      int idx = it * 256 + tid;
      int r = idx >> 7, c16 = idx & 127;        // row, 16B-chunk
      const char* src = sq + (c16 >> 5) * 8448 + r * 528 + (c16 & 31) * 16;
      *(short8*)(SE + (((size_t)(b * 1024 + qb + qh * 16 + r) * 16 + h) << 10) + c16 * 8) =
          *(const short8*)src;
    }
  }
}

// ---------------- kernel 4: E = exp(S + bias) in-place, lsum -> linv ----------------
// Block (b, lq): all 16 h x all 1024 lk. Bias staged coalesced -> LDS [256][17].
__global__ __launch_bounds__(256) void exp_k(
    us* __restrict__ SE, const float* __restrict__ bias, float* __restrict__ linv) {
  __shared__ float bt[4352];  // [256 lk][17]
  int tid = threadIdx.x;
  int la = tid & 15, h = tid >> 4;  // h = 4*w + lg
  int bid = blockIdx.x;
  int lq = bid & 1023, b = bid >> 10;
  const float* brow = bias + ((size_t)b << 24) + ((size_t)lq << 14);
  us* row = SE + (((size_t)(b * 1024 + lq) * 16 + h) << 10);
  float lsum = 0.f;

#pragma unroll 1
  for (int ch = 0; ch < 4; ++ch) {
    int lk0 = ch * 256;
    __syncthreads();  // previous chunk's bt reads done
#pragma unroll
    for (int i = 0; i < 4; ++i) {
      int f = i * 256 + tid;             // f32x4 index in [256 lk][4 h4]
      int lk = f >> 2, h4 = f & 3;
      f32x4 v = *(const f32x4*)(brow + (size_t)(lk0 + lk) * 16 + h4 * 4);
      int base = lk * 17 + h4 * 4;
      bt[base] = v.x; bt[base + 1] = v.y; bt[base + 2] = v.z; bt[base + 3] = v.w;
    }
    __syncthreads();
#pragma unroll
    for (int j = 0; j < 4; ++j) {
      int lkl = 4 * (la + 16 * j);
      u16x4 sv = *(const u16x4*)(row + lk0 + lkl);
      u16x4 ev;
#pragma unroll
      for (int i = 0; i < 4; ++i) {
        float e = __expf(h2f(sv[i]) + bt[(lkl + i) * 17 + h]);
        lsum += e;
        ev[i] = f2b(e);
      }
      *(u16x4*)(row + lk0 + lkl) = ev;
    }
  }
#pragma unroll
  for (int d = 1; d < 16; d <<= 1) lsum += __shfl_xor(lsum, d);
  if (la == 0) linv[((size_t)(b * 16 + h) << 10) + lq] = 1.f / lsum;
}

// ---------------- kernel 5: PV + transposed probs + gate ----------------
// Block (b,h,32q), 4 waves x 256 lk. E tile staged once into XOR-swizzled LDS,
// feeds both the probs transpose (coalesced f32x4 out) and PV MFMA A-frags.
__global__ __launch_bounds__(256) void pv_k(
    const us* __restrict__ E, const us* __restrict__ Vt,
    const float* __restrict__ linv, const float* __restrict__ G,
    float* __restrict__ outa, us* __restrict__ Ybf) {
  __shared__ char sm[49792];
  float* lv = (float*)(sm + 49664);
  int tid = threadIdx.x, lane = tid & 63, w = tid >> 6;
  int la = lane & 15, lg = lane >> 4;
  int bid = blockIdx.x;
  int g = bid >> 8, qt = (bid >> 3) & 31, xx = bid & 7;
  int bh = g * 8 + xx;
  int b = bh >> 4, h = bh & 15;
  int qb = qt * 32;
  if (tid < 32) lv[tid] = linv[((size_t)bh << 10) + qb + tid];
  __syncthreads();
  char* pb = sm + w * 4096;  // [32 q][64 lk] bf16, chunk-XOR swizzle
  const us* Vh = Vt + (size_t)bh * 65536;
  f32x4 yacc[2][4] = {};
  int lkw = w * 256;

#pragma unroll 1
  for (int cc = 0; cc < 4; ++cc) {
    int lk0 = lkw + cc * 64;
    // stage E tile (reg-staged so dest can be swizzled)
#pragma unroll
    for (int it = 0; it < 4; ++it) {
      int ci = it * 64 + lane;
      int q = ci >> 3, c16 = ci & 7;
      short8 ev = *(const short8*)(E + (((size_t)(b * 1024 + qb + q) * 16 + h) << 10) + lk0 + c16 * 8);
      *(short8*)(pb + q * 128 + ((c16 * 16) ^ ((q & 7) << 4))) = ev;
    }
    // transposed probs: outa[b][lk][h][qb..qb+32)
#pragma unroll
    for (int it = 0; it < 8; ++it) {
      int idx = it * 64 + lane;
      int lkL = idx >> 3, q4 = idx & 7;
      f32x4 ov;
#pragma unroll
      for (int i = 0; i < 4; ++i) {
        int q = q4 * 4 + i;
        us e = *(const us*)(pb + q * 128 + ((2 * lkL) ^ ((q & 7) << 4)));
        ov[i] = b2f(e) * lv[q];
      }
      *(f32x4*)(outa + (((size_t)(b * 1024 + lk0 + lkL) * 16 + h) << 10) + qb + q4 * 4) = ov;
    }
    // PV
#pragma unroll
    for (int ks = 0; ks < 2; ++ks) {
      short8 pa[2];
#pragma unroll
      for (int qh = 0; qh < 2; ++qh) {
        int row = qh * 16 + la;
        pa[qh] = *(const short8*)(pb + row * 128 + ((ks * 64 + lg * 16) ^ ((row & 7) << 4)));
      }
#pragma unroll
      for (int ni = 0; ni < 4; ++ni) {
        short8 vf = *(const short8*)(Vh + (size_t)(ni * 16 + la) * 1024 + lk0 + ks * 32 + lg * 8);
        yacc[0][ni] = MFMA16(pa[0], vf, yacc[0][ni]);
        yacc[1][ni] = MFMA16(pa[1], vf, yacc[1][ni]);
      }
    }
  }

  // cross-wave O reduce + linv + gate
  float* red = (float*)(sm + 16384);  // [4 w][32 r][65]
#pragma unroll
  for (int qh = 0; qh < 2; ++qh)
#pragma unroll
    for (int ni = 0; ni < 4; ++ni)
#pragma unroll
      for (int j = 0; j < 4; ++j) {
        int r = qh * 16 + lg * 4 + j, c = ni * 16 + la;
        red[w * 2080 + r * 65 + c] = yacc[qh][ni][j];
      }
  __syncthreads();
#pragma unroll
  for (int rr = 0; rr < 8; ++rr) {
    int e = rr * 256 + tid;
    int r = e >> 6, c = e & 63;
    float s = red[r * 65 + c] + red[2080 + r * 65 + c] +
              red[4160 + r * 65 + c] + red[6240 + r * 65 + c];
    size_t gi = (((size_t)(b * 1024 + qb + r)) << 10) + h * 64 + c;
    Ybf[gi] = f2b(s * lv[r] * G[gi]);
  }
}

// ---------------- kernel 6: output projection ----------------
__global__ __launch_bounds__(256) void gemm_out_k(
    const us* __restrict__ Ybf, const us* __restrict__ Wobf,
    const float* __restrict__ bo, float* __restrict__ outy) {
  __shared__ char sm[32768];
  int bid = blockIdx.x;
  int swz = (bid & 7) * 16 + (bid >> 3);
  int tileM = swz >> 3, tileN = swz & 7;
  f32x4 acc[4][4] = {};
  gemm_main(Ybf, Wobf, tileM * 128, tileN * 128, acc, sm);
  int lane = threadIdx.x & 63, wid = threadIdx.x >> 6;
  int wr = wid >> 1, wc = wid & 1;
#pragma unroll
  for (int mi = 0; mi < 4; ++mi)
#pragma unroll
    for (int ni = 0; ni < 4; ++ni)
#pragma unroll
      for (int j = 0; j < 4; ++j) {
        int row = tileM * 128 + wr * 64 + mi * 16 + ((lane >> 4) << 2) + j;
        int col = tileN * 128 + wc * 64 + ni * 16 + (lane & 15);
        outy[(size_t)row * 1024 + col] = acc[mi][ni][j] + bo[col];
      }
}

extern "C" void kernel_launch(void* const* d_in, const int* in_sizes, int n_in,
                              void* d_out, int out_size, void* d_ws, size_t ws_size,
                              hipStream_t stream) {
  const float* x     = (const float*)d_in[0];
  const float* bias  = (const float*)d_in[1];
  const float* wproj = (const float*)d_in[2];
  const float* wo    = (const float*)d_in[3];
  const float* bo    = (const float*)d_in[4];
  const float* wg    = (const float*)d_in[5];
  const float* bg    = (const float*)d_in[6];
  float* outy = (float*)d_out;
  float* outa = outy + 2097152;  // y (2M f32), then probs (B,Lk,H,Lq) f32

  char* ws = (char*)d_ws;
  us*    Xbf  = (us*)(ws);
  us*    Wbf  = (us*)(ws + 4  * 1024 * 1024);
  us*    Wobf = (us*)(ws + 12 * 1024 * 1024);
  us*    Qb   = (us*)(ws + 14 * 1024 * 1024);
  us*    Kb   = (us*)(ws + 18 * 1024 * 1024);
  us*    Vt   = (us*)(ws + 22 * 1024 * 1024);
  float* G    = (float*)(ws + 26 * 1024 * 1024);
  us*    Ybf  = (us*)(ws + 34 * 1024 * 1024);
  us*    SE   = (us*)(ws + (size_t)38 * 1024 * 1024);   // 64 MB: S fp16 -> E bf16 in-place
  float* linv = (float*)(ws + (size_t)102 * 1024 * 1024); // 128 KB
  if (ws_size < (size_t)103 * 1024 * 1024) return;

  prep_k<<<dim3(7168), dim3(256), 0, stream>>>(x, wproj, wg, wo, Xbf, Wbf, Wobf);
  gemm_qkvg_k<<<dim3(512), dim3(256), 0, stream>>>(Xbf, Wbf, Qb, Kb, Vt, G, bg);
  qk_k<<<dim3(1024), dim3(256), 0, stream>>>(Qb, Kb, SE);
  exp_k<<<dim3(2048), dim3(256), 0, stream>>>(SE, bias, linv);
  pv_k<<<dim3(1024), dim3(256), 0, stream>>>(SE, Vt, linv, G, outa, Ybf);
  gemm_out_k<<<dim3(128), dim3(256), 0, stream>>>(Ybf, Wobf, bo, outy);
}

// Round 8
// 203.194 us; speedup vs baseline: 1.3070x; 1.0198x over previous
//
#include <hip/hip_runtime.h>
#include <hip/hip_bf16.h>
#include <stdint.h>

typedef __attribute__((ext_vector_type(4))) float f32x4;
typedef __attribute__((ext_vector_type(8))) short short8;
typedef __attribute__((ext_vector_type(4))) unsigned short u16x4;
typedef unsigned short us;

#define DEV __device__ __forceinline__
#define MFMA16(a, b, c) __builtin_amdgcn_mfma_f32_16x16x32_bf16(a, b, c, 0, 0, 0)

DEV us f2b(float x) {
  union { float f; uint32_t u; } c; c.f = x;
  uint32_t r = (c.u + 0x7fffu + ((c.u >> 16) & 1u)) >> 16;
  return (us)r;
}
DEV float b2f(us x) {
  union { uint32_t u; float f; } c; c.u = ((uint32_t)x) << 16;
  return c.f;
}

DEV void gload_lds16(const void* g, void* l) {
  __builtin_amdgcn_global_load_lds((const __attribute__((address_space(1))) void*)g,
                                   (__attribute__((address_space(3))) void*)l, 16, 0, 0);
}

// ---------------- kernel 1: fp32 -> bf16 conversions ----------------
__global__ __launch_bounds__(256) void prep_k(
    const float* __restrict__ x, const float* __restrict__ wproj,
    const float* __restrict__ wg, const float* __restrict__ wo,
    us* __restrict__ Xbf, us* __restrict__ Wbf, us* __restrict__ Wobf) {
  int i = blockIdx.x * 256 + threadIdx.x;
  const float* src; us* dst;
  if (i < 524288)               { src = x     + (size_t)i * 4;                  dst = Xbf + (size_t)i * 4; }
  else if (i < 524288 + 786432) { int j = i - 524288;            src = wproj + (size_t)j * 4; dst = Wbf + (size_t)j * 4; }
  else if (i < 524288 + 786432 + 262144) { int j = i - (524288 + 786432); src = wg + (size_t)j * 4; dst = Wbf + 3145728 + (size_t)j * 4; }
  else                          { int j = i - (524288 + 786432 + 262144); src = wo + (size_t)j * 4; dst = Wobf + (size_t)j * 4; }
  f32x4 v = *(const f32x4*)src;
  u16x4 o; o.x = f2b(v.x); o.y = f2b(v.y); o.z = f2b(v.z); o.w = f2b(v.w);
  *(u16x4*)dst = o;
}

// ---------------- shared GEMM core (m97-style, 128x128) ----------------
DEV void gemm_stage(char* sm, const us* A, const us* Bw,
                    int tileMrow, int tileNrow, int buf, int kt, int lane, int wid) {
  const char* gA = (const char*)A;
  const char* gB = (const char*)Bw;
#pragma unroll
  for (int i = 0; i < 2; ++i) {
    int c = wid * 2 + i;
    int off = c * 1024 + lane * 16;
    int r = off >> 6, cb = off & 63;
    gload_lds16(gA + ((size_t)(tileMrow + r) * 2048) + kt * 64 + cb, sm + buf * 8192 + c * 1024);
    gload_lds16(gB + ((size_t)(tileNrow + r) * 2048) + kt * 64 + cb, sm + 16384 + buf * 8192 + c * 1024);
  }
}

DEV void gemm_main(const us* A, const us* Bw,
                   int tileMrow, int tileNrow, f32x4 acc[4][4], char* sm) {
  int tid = threadIdx.x, lane = tid & 63, wid = tid >> 6;
  int wr = wid >> 1, wc = wid & 1;
  gemm_stage(sm, A, Bw, tileMrow, tileNrow, 0, 0, lane, wid);
  for (int kt = 0; kt < 32; ++kt) {
    __syncthreads();
    if (kt < 31) gemm_stage(sm, A, Bw, tileMrow, tileNrow, (kt + 1) & 1, kt + 1, lane, wid);
    int ab = (kt & 1) * 8192;
    int rb = (lane & 15) * 64 + ((lane >> 4) * 16);
    short8 af[4], bf[4];
#pragma unroll
    for (int mi = 0; mi < 4; ++mi)
      af[mi] = *(const short8*)(sm + ab + (wr * 64 + mi * 16) * 64 + rb);
#pragma unroll
    for (int ni = 0; ni < 4; ++ni)
      bf[ni] = *(const short8*)(sm + 16384 + ab + (wc * 64 + ni * 16) * 64 + rb);
#pragma unroll
    for (int mi = 0; mi < 4; ++mi)
#pragma unroll
      for (int ni = 0; ni < 4; ++ni)
        acc[mi][ni] = MFMA16(af[mi], bf[ni], acc[mi][ni]);
  }
}

// ---------------- kernel 2: QKV+gate projection ----------------
__global__ __launch_bounds__(256) void gemm_qkvg_k(
    const us* __restrict__ Xbf, const us* __restrict__ Wbf,
    us* __restrict__ Qb, us* __restrict__ Kb, us* __restrict__ Vt,
    float* __restrict__ G, const float* __restrict__ bg) {
  __shared__ char sm[32768];
  int bid = blockIdx.x;
  int swz = (bid & 7) * 64 + (bid >> 3);
  int tileM = swz >> 5, tileN = swz & 31;
  f32x4 acc[4][4] = {};
  gemm_main(Xbf, Wbf, tileM * 128, tileN * 128, acc, sm);
  int lane = threadIdx.x & 63, wid = threadIdx.x >> 6;
  int wr = wid >> 1, wc = wid & 1;
#pragma unroll
  for (int mi = 0; mi < 4; ++mi)
#pragma unroll
    for (int ni = 0; ni < 4; ++ni)
#pragma unroll
      for (int j = 0; j < 4; ++j) {
        int row = tileM * 128 + wr * 64 + mi * 16 + ((lane >> 4) << 2) + j;
        int col = tileN * 128 + wc * 64 + ni * 16 + (lane & 15);
        float v = acc[mi][ni][j];
        int b = row >> 10, l = row & 1023;
        if (col < 3072) {
          int h = col / 192, r = col - h * 192;
          size_t base = ((size_t)(b * 16 + h) * 1024 + l) * 64;
          if (r < 64)        Qb[base + r] = f2b(v * 0.125f);
          else if (r < 128)  Kb[base + (r - 64)] = f2b(v);
          else               Vt[((size_t)(b * 16 + h) * 64 + (r - 128)) * 1024 + l] = f2b(v);
        } else {
          int e = col - 3072;
          float s = v + bg[e];
          G[(size_t)row * 1024 + e] = 1.f / (1.f + __expf(-s));
        }
      }
}

// ---------------- kernel 3: fused QK^T + bias + exp -> E, lsum partials ----------------
// Block (b, qt:16 q-rows, kc: 256-lk chunk) x ALL 16 heads. 8 waves, 2 heads/wave.
// Bias double-buffered in LDS (coalesced loads); swapped MFMA (lane=q, reg=lk)
// with bias as C-init; E stored bf16 direct from regs (lk-contiguous).
__global__ __launch_bounds__(512, 4) void qke_k(
    const us* __restrict__ Qb, const us* __restrict__ Kb,
    const float* __restrict__ bias, us* __restrict__ E,
    float* __restrict__ lpart) {
  __shared__ float bt[2][8704];   // [16 q][32 lk][17 (16h+pad)] per buffer
  int tid = threadIdx.x, lane = tid & 63, w = tid >> 6;
  int la = lane & 15, lg = lane >> 4;
  int bid = blockIdx.x;
  int grp = bid & 7, qt = bid >> 3;        // grp = b*4+kc -> XCD-pinned per group
  int b = grp >> 2, kc = grp & 3;
  int lq0 = qt * 16, lk00 = kc * 256;
  int h0 = w * 2;

  short8 qf[2][2];
#pragma unroll
  for (int t = 0; t < 2; ++t) {
    size_t bh = (size_t)(b * 16 + h0 + t);
#pragma unroll
    for (int ks = 0; ks < 2; ++ks)
      qf[t][ks] = *(const short8*)(Qb + bh * 65536 + (size_t)(lq0 + la) * 64 + ks * 32 + lg * 8);
  }

  const float* bsrc = bias + ((size_t)b << 24) + ((size_t)lq0 << 14);
  // stage chunk 0
#pragma unroll
  for (int i = 0; i < 4; ++i) {
    int f = i * 512 + tid;
    int h4 = f & 3, lk = (f >> 2) & 31, q = f >> 7;
    f32x4 v = *(const f32x4*)(bsrc + ((size_t)q << 14) + ((size_t)(lk00 + lk) << 4) + h4 * 4);
    float* d = &bt[0][(q * 32 + lk) * 17 + h4 * 4];
    d[0] = v.x; d[1] = v.y; d[2] = v.z; d[3] = v.w;
  }

  float lacc[2] = {0.f, 0.f};
#pragma unroll 1
  for (int sc = 0; sc < 8; ++sc) {
    __syncthreads();
    if (sc < 7) {
      int lkg2 = lk00 + (sc + 1) * 32;
      float* bd = bt[(sc + 1) & 1];
#pragma unroll
      for (int i = 0; i < 4; ++i) {
        int f = i * 512 + tid;
        int h4 = f & 3, lk = (f >> 2) & 31, q = f >> 7;
        f32x4 v = *(const f32x4*)(bsrc + ((size_t)q << 14) + ((size_t)(lkg2 + lk) << 4) + h4 * 4);
        float* d = &bd[(q * 32 + lk) * 17 + h4 * 4];
        d[0] = v.x; d[1] = v.y; d[2] = v.z; d[3] = v.w;
      }
    }
    const float* btc = bt[sc & 1];
    int lkg = lk00 + sc * 32;
#pragma unroll
    for (int t = 0; t < 2; ++t) {
      int h = h0 + t;
      const us* Kh = Kb + (size_t)(b * 16 + h) * 65536;
#pragma unroll
      for (int fr = 0; fr < 2; ++fr) {
        const us* kr = Kh + (size_t)(lkg + fr * 16 + la) * 64 + lg * 8;
        short8 kf0 = *(const short8*)kr;
        short8 kf1 = *(const short8*)(kr + 32);
        f32x4 a;
#pragma unroll
        for (int j = 0; j < 4; ++j)
          a[j] = btc[(la * 32 + fr * 16 + lg * 4 + j) * 17 + h];
        a = MFMA16(kf0, qf[t][0], a);
        a = MFMA16(kf1, qf[t][1], a);
        u16x4 ev;
#pragma unroll
        for (int j = 0; j < 4; ++j) {
          float e = __expf(a[j]);
          lacc[t] += e;
          ev[j] = f2b(e);
        }
        *(u16x4*)(E + (((size_t)(b * 1024 + lq0 + la) * 16 + h) << 10) + lkg + fr * 16 + lg * 4) = ev;
      }
    }
  }
  // lsum: reduce across lg (lanes sharing q=la), store per-kc partial
#pragma unroll
  for (int t = 0; t < 2; ++t) {
    float s = lacc[t];
    s += __shfl_xor(s, 16);
    s += __shfl_xor(s, 32);
    if (lg == 0) lpart[kc * 32768 + (b * 16 + h0 + t) * 1024 + lq0 + la] = s;
  }
}

// ---------------- kernel 4: PV + transposed probs + gate ----------------
// Block (b,h,32q), 4 waves x 256 lk. linv merged in-block from lpart.
__global__ __launch_bounds__(256) void pv_k(
    const us* __restrict__ E, const us* __restrict__ Vt,
    const float* __restrict__ lpart, const float* __restrict__ G,
    float* __restrict__ outa, us* __restrict__ Ybf) {
  __shared__ char sm[49792];
  float* lv = (float*)(sm + 49664);
  int tid = threadIdx.x, lane = tid & 63, w = tid >> 6;
  int la = lane & 15, lg = lane >> 4;
  int bid = blockIdx.x;
  int g = bid >> 8, qt = (bid >> 3) & 31, xx = bid & 7;
  int bh = g * 8 + xx;
  int b = bh >> 4, h = bh & 15;
  int qb = qt * 32;
  if (tid < 32) {
    int r = bh * 1024 + qb + tid;
    float s = lpart[r] + lpart[32768 + r] + lpart[65536 + r] + lpart[98304 + r];
    lv[tid] = 1.f / s;
  }
  __syncthreads();
  char* pb = sm + w * 4096;  // [32 q][64 lk] bf16, chunk-XOR swizzle
  const us* Vh = Vt + (size_t)bh * 65536;
  f32x4 yacc[2][4] = {};
  int lkw = w * 256;

#pragma unroll 1
  for (int cc = 0; cc < 4; ++cc) {
    int lk0 = lkw + cc * 64;
    // stage E tile (reg-staged so dest can be swizzled)
#pragma unroll
    for (int it = 0; it < 4; ++it) {
      int ci = it * 64 + lane;
      int q = ci >> 3, c16 = ci & 7;
      short8 ev = *(const short8*)(E + (((size_t)(b * 1024 + qb + q) * 16 + h) << 10) + lk0 + c16 * 8);
      *(short8*)(pb + q * 128 + ((c16 * 16) ^ ((q & 7) << 4))) = ev;
    }
    // transposed probs: outa[b][lk][h][qb..qb+32)
#pragma unroll
    for (int it = 0; it < 8; ++it) {
      int idx = it * 64 + lane;
      int lkL = idx >> 3, q4 = idx & 7;
      f32x4 ov;
#pragma unroll
      for (int i = 0; i < 4; ++i) {
        int q = q4 * 4 + i;
        us e = *(const us*)(pb + q * 128 + ((2 * lkL) ^ ((q & 7) << 4)));
        ov[i] = b2f(e) * lv[q];
      }
      *(f32x4*)(outa + (((size_t)(b * 1024 + lk0 + lkL) * 16 + h) << 10) + qb + q4 * 4) = ov;
    }
    // PV
#pragma unroll
    for (int ks = 0; ks < 2; ++ks) {
      short8 pa[2];
#pragma unroll
      for (int qh = 0; qh < 2; ++qh) {
        int row = qh * 16 + la;
        pa[qh] = *(const short8*)(pb + row * 128 + ((ks * 64 + lg * 16) ^ ((row & 7) << 4)));
      }
#pragma unroll
      for (int ni = 0; ni < 4; ++ni) {
        short8 vf = *(const short8*)(Vh + (size_t)(ni * 16 + la) * 1024 + lk0 + ks * 32 + lg * 8);
        yacc[0][ni] = MFMA16(pa[0], vf, yacc[0][ni]);
        yacc[1][ni] = MFMA16(pa[1], vf, yacc[1][ni]);
      }
    }
  }

  // cross-wave O reduce + linv + gate
  float* red = (float*)(sm + 16384);  // [4 w][32 r][65]
#pragma unroll
  for (int qh = 0; qh < 2; ++qh)
#pragma unroll
    for (int ni = 0; ni < 4; ++ni)
#pragma unroll
      for (int j = 0; j < 4; ++j) {
        int r = qh * 16 + lg * 4 + j, c = ni * 16 + la;
        red[w * 2080 + r * 65 + c] = yacc[qh][ni][j];
      }
  __syncthreads();
#pragma unroll
  for (int rr = 0; rr < 8; ++rr) {
    int e = rr * 256 + tid;
    int r = e >> 6, c = e & 63;
    float s = red[r * 65 + c] + red[2080 + r * 65 + c] +
              red[4160 + r * 65 + c] + red[6240 + r * 65 + c];
    size_t gi = (((size_t)(b * 1024 + qb + r)) << 10) + h * 64 + c;
    Ybf[gi] = f2b(s * lv[r] * G[gi]);
  }
}

// ---------------- kernel 5: output projection ----------------
__global__ __launch_bounds__(256) void gemm_out_k(
    const us* __restrict__ Ybf, const us* __restrict__ Wobf,
    const float* __restrict__ bo, float* __restrict__ outy) {
  __shared__ char sm[32768];
  int bid = blockIdx.x;
  int swz = (bid & 7) * 16 + (bid >> 3);
  int tileM = swz >> 3, tileN = swz & 7;
  f32x4 acc[4][4] = {};
  gemm_main(Ybf, Wobf, tileM * 128, tileN * 128, acc, sm);
  int lane = threadIdx.x & 63, wid = threadIdx.x >> 6;
  int wr = wid >> 1, wc = wid & 1;
#pragma unroll
  for (int mi = 0; mi < 4; ++mi)
#pragma unroll
    for (int ni = 0; ni < 4; ++ni)
#pragma unroll
      for (int j = 0; j < 4; ++j) {
        int row = tileM * 128 + wr * 64 + mi * 16 + ((lane >> 4) << 2) + j;
        int col = tileN * 128 + wc * 64 + ni * 16 + (lane & 15);
        outy[(size_t)row * 1024 + col] = acc[mi][ni][j] + bo[col];
      }
}

extern "C" void kernel_launch(void* const* d_in, const int* in_sizes, int n_in,
                              void* d_out, int out_size, void* d_ws, size_t ws_size,
                              hipStream_t stream) {
  const float* x     = (const float*)d_in[0];
  const float* bias  = (const float*)d_in[1];
  const float* wproj = (const float*)d_in[2];
  const float* wo    = (const float*)d_in[3];
  const float* bo    = (const float*)d_in[4];
  const float* wg    = (const float*)d_in[5];
  const float* bg    = (const float*)d_in[6];
  float* outy = (float*)d_out;
  float* outa = outy + 2097152;  // y (2M f32), then probs (B,Lk,H,Lq) f32

  char* ws = (char*)d_ws;
  us*    Xbf  = (us*)(ws);
  us*    Wbf  = (us*)(ws + 4  * 1024 * 1024);
  us*    Wobf = (us*)(ws + 12 * 1024 * 1024);
  us*    Qb   = (us*)(ws + 14 * 1024 * 1024);
  us*    Kb   = (us*)(ws + 18 * 1024 * 1024);
  us*    Vt   = (us*)(ws + 22 * 1024 * 1024);
  float* G    = (float*)(ws + 26 * 1024 * 1024);
  us*    Ybf  = (us*)(ws + 34 * 1024 * 1024);
  float* lpart= (float*)(ws + (size_t)38 * 1024 * 1024);   // 512 KB
  us*    E    = (us*)   (ws + (size_t)40 * 1024 * 1024);   // 64 MB bf16
  if (ws_size < (size_t)104 * 1024 * 1024) return;

  prep_k<<<dim3(7168), dim3(256), 0, stream>>>(x, wproj, wg, wo, Xbf, Wbf, Wobf);
  gemm_qkvg_k<<<dim3(512), dim3(256), 0, stream>>>(Xbf, Wbf, Qb, Kb, Vt, G, bg);
  qke_k<<<dim3(512), dim3(512), 0, stream>>>(Qb, Kb, bias, E, lpart);
  pv_k<<<dim3(1024), dim3(256), 0, stream>>>(E, Vt, lpart, G, outa, Ybf);
  gemm_out_k<<<dim3(128), dim3(256), 0, stream>>>(Ybf, Wobf, bo, outy);
}

// Round 9
// 200.719 us; speedup vs baseline: 1.3231x; 1.0123x over previous
//
#include <hip/hip_runtime.h>
#include <hip/hip_bf16.h>
#include <stdint.h>

typedef __attribute__((ext_vector_type(4))) float f32x4;
typedef __attribute__((ext_vector_type(8))) short short8;
typedef __attribute__((ext_vector_type(4))) unsigned short u16x4;
typedef unsigned short us;

#define DEV __device__ __forceinline__
#define MFMA16(a, b, c) __builtin_amdgcn_mfma_f32_16x16x32_bf16(a, b, c, 0, 0, 0)

DEV us f2b(float x) {
  union { float f; uint32_t u; } c; c.f = x;
  uint32_t r = (c.u + 0x7fffu + ((c.u >> 16) & 1u)) >> 16;
  return (us)r;
}
DEV float b2f(us x) {
  union { uint32_t u; float f; } c; c.u = ((uint32_t)x) << 16;
  return c.f;
}

DEV void gload_lds16(const void* g, void* l) {
  __builtin_amdgcn_global_load_lds((const __attribute__((address_space(1))) void*)g,
                                   (__attribute__((address_space(3))) void*)l, 16, 0, 0);
}

// ---------------- kernel 1: fp32 -> bf16 conversions ----------------
__global__ __launch_bounds__(256) void prep_k(
    const float* __restrict__ x, const float* __restrict__ wproj,
    const float* __restrict__ wg, const float* __restrict__ wo,
    us* __restrict__ Xbf, us* __restrict__ Wbf, us* __restrict__ Wobf) {
  int i = blockIdx.x * 256 + threadIdx.x;
  const float* src; us* dst;
  if (i < 524288)               { src = x     + (size_t)i * 4;                  dst = Xbf + (size_t)i * 4; }
  else if (i < 524288 + 786432) { int j = i - 524288;            src = wproj + (size_t)j * 4; dst = Wbf + (size_t)j * 4; }
  else if (i < 524288 + 786432 + 262144) { int j = i - (524288 + 786432); src = wg + (size_t)j * 4; dst = Wbf + 3145728 + (size_t)j * 4; }
  else                          { int j = i - (524288 + 786432 + 262144); src = wo + (size_t)j * 4; dst = Wobf + (size_t)j * 4; }
  f32x4 v = *(const f32x4*)src;
  u16x4 o; o.x = f2b(v.x); o.y = f2b(v.y); o.z = f2b(v.z); o.w = f2b(v.w);
  *(u16x4*)dst = o;
}

// ---------------- shared GEMM core (m97-style, 128x128) ----------------
DEV void gemm_stage(char* sm, const us* A, const us* Bw,
                    int tileMrow, int tileNrow, int buf, int kt, int lane, int wid) {
  const char* gA = (const char*)A;
  const char* gB = (const char*)Bw;
#pragma unroll
  for (int i = 0; i < 2; ++i) {
    int c = wid * 2 + i;
    int off = c * 1024 + lane * 16;
    int r = off >> 6, cb = off & 63;
    gload_lds16(gA + ((size_t)(tileMrow + r) * 2048) + kt * 64 + cb, sm + buf * 8192 + c * 1024);
    gload_lds16(gB + ((size_t)(tileNrow + r) * 2048) + kt * 64 + cb, sm + 16384 + buf * 8192 + c * 1024);
  }
}

DEV void gemm_main(const us* A, const us* Bw,
                   int tileMrow, int tileNrow, f32x4 acc[4][4], char* sm) {
  int tid = threadIdx.x, lane = tid & 63, wid = tid >> 6;
  int wr = wid >> 1, wc = wid & 1;
  gemm_stage(sm, A, Bw, tileMrow, tileNrow, 0, 0, lane, wid);
  for (int kt = 0; kt < 32; ++kt) {
    __syncthreads();
    if (kt < 31) gemm_stage(sm, A, Bw, tileMrow, tileNrow, (kt + 1) & 1, kt + 1, lane, wid);
    int ab = (kt & 1) * 8192;
    int rb = (lane & 15) * 64 + ((lane >> 4) * 16);
    short8 af[4], bf[4];
#pragma unroll
    for (int mi = 0; mi < 4; ++mi)
      af[mi] = *(const short8*)(sm + ab + (wr * 64 + mi * 16) * 64 + rb);
#pragma unroll
    for (int ni = 0; ni < 4; ++ni)
      bf[ni] = *(const short8*)(sm + 16384 + ab + (wc * 64 + ni * 16) * 64 + rb);
#pragma unroll
    for (int mi = 0; mi < 4; ++mi)
#pragma unroll
      for (int ni = 0; ni < 4; ++ni)
        acc[mi][ni] = MFMA16(af[mi], bf[ni], acc[mi][ni]);
  }
}

// ---------------- kernel 2: QKV+gate projection ----------------
__global__ __launch_bounds__(256) void gemm_qkvg_k(
    const us* __restrict__ Xbf, const us* __restrict__ Wbf,
    us* __restrict__ Qb, us* __restrict__ Kb, us* __restrict__ Vt,
    float* __restrict__ G, const float* __restrict__ bg) {
  __shared__ char sm[32768];
  int bid = blockIdx.x;
  int swz = (bid & 7) * 64 + (bid >> 3);
  int tileM = swz >> 5, tileN = swz & 31;
  f32x4 acc[4][4] = {};
  gemm_main(Xbf, Wbf, tileM * 128, tileN * 128, acc, sm);
  int lane = threadIdx.x & 63, wid = threadIdx.x >> 6;
  int wr = wid >> 1, wc = wid & 1;
#pragma unroll
  for (int mi = 0; mi < 4; ++mi)
#pragma unroll
    for (int ni = 0; ni < 4; ++ni)
#pragma unroll
      for (int j = 0; j < 4; ++j) {
        int row = tileM * 128 + wr * 64 + mi * 16 + ((lane >> 4) << 2) + j;
        int col = tileN * 128 + wc * 64 + ni * 16 + (lane & 15);
        float v = acc[mi][ni][j];
        int b = row >> 10, l = row & 1023;
        if (col < 3072) {
          int h = col / 192, r = col - h * 192;
          size_t base = ((size_t)(b * 16 + h) * 1024 + l) * 64;
          if (r < 64)        Qb[base + r] = f2b(v * 0.125f);
          else if (r < 128)  Kb[base + (r - 64)] = f2b(v);
          else               Vt[((size_t)(b * 16 + h) * 64 + (r - 128)) * 1024 + l] = f2b(v);
        } else {
          int e = col - 3072;
          float s = v + bg[e];
          G[(size_t)row * 1024 + e] = 1.f / (1.f + __expf(-s));
        }
      }
}

// ---------------- kernel 3: fused QK^T + bias + exp -> E, lsum partials ----------------
// Block (b, qt:16 q-rows, kc: 256-lk chunk) x ALL 16 heads. 8 waves, 2 heads/wave.
// Bias tile double-buffered in LDS as [h][q][lk+pad36] with XOR swizzle
// (lk ^ ((h&7)<<2)): writes 2-way (free), reads one b128/lane at uniform banks.
__global__ __launch_bounds__(512, 4) void qke_k(
    const us* __restrict__ Qb, const us* __restrict__ Kb,
    const float* __restrict__ bias, us* __restrict__ E,
    float* __restrict__ lpart) {
  __shared__ float bt[2][16][16][36];   // [buf][h][q][lk32 + pad4]
  int tid = threadIdx.x, lane = tid & 63, w = tid >> 6;
  int la = lane & 15, lg = lane >> 4;
  int bid = blockIdx.x;
  int grp = bid & 7, qt = bid >> 3;        // grp = b*4+kc -> XCD-pinned per group
  int b = grp >> 2, kc = grp & 3;
  int lq0 = qt * 16, lk00 = kc * 256;
  int h0 = w * 2;

  short8 qf[2][2];
#pragma unroll
  for (int t = 0; t < 2; ++t) {
    size_t bh = (size_t)(b * 16 + h0 + t);
#pragma unroll
    for (int ks = 0; ks < 2; ++ks)
      qf[t][ks] = *(const short8*)(Qb + bh * 65536 + (size_t)(lq0 + la) * 64 + ks * 32 + lg * 8);
  }

  const float* bsrc = bias + ((size_t)b << 24) + ((size_t)lq0 << 14);
  // stage chunk 0
#pragma unroll
  for (int i = 0; i < 4; ++i) {
    int f = i * 512 + tid;
    int h4 = (f & 3) * 4, lk = (f >> 2) & 31, q = f >> 7;
    f32x4 v = *(const f32x4*)(bsrc + ((size_t)q << 14) + ((size_t)(lk00 + lk) << 4) + h4);
#pragma unroll
    for (int e = 0; e < 4; ++e) {
      int h = h4 + e;
      bt[0][h][q][lk ^ ((h & 7) << 2)] = v[e];
    }
  }

  float lacc[2] = {0.f, 0.f};
#pragma unroll 1
  for (int sc = 0; sc < 8; ++sc) {
    __syncthreads();
    if (sc < 7) {
      int lkg2 = lk00 + (sc + 1) * 32;
      int nb = (sc + 1) & 1;
#pragma unroll
      for (int i = 0; i < 4; ++i) {
        int f = i * 512 + tid;
        int h4 = (f & 3) * 4, lk = (f >> 2) & 31, q = f >> 7;
        f32x4 v = *(const f32x4*)(bsrc + ((size_t)q << 14) + ((size_t)(lkg2 + lk) << 4) + h4);
#pragma unroll
        for (int e = 0; e < 4; ++e) {
          int h = h4 + e;
          bt[nb][h][q][lk ^ ((h & 7) << 2)] = v[e];
        }
      }
    }
    int cb = sc & 1;
    int lkg = lk00 + sc * 32;
#pragma unroll
    for (int t = 0; t < 2; ++t) {
      int h = h0 + t;
      const us* Kh = Kb + (size_t)(b * 16 + h) * 65536;
#pragma unroll
      for (int fr = 0; fr < 2; ++fr) {
        const us* kr = Kh + (size_t)(lkg + fr * 16 + la) * 64 + lg * 8;
        short8 kf0 = *(const short8*)kr;
        short8 kf1 = *(const short8*)(kr + 32);
        // bias fragment: one b128, banks uniform by construction
        int lkb = (fr * 16 + lg * 4) ^ ((h & 7) << 2);
        f32x4 a = *(const f32x4*)&bt[cb][h][la][lkb];
        a = MFMA16(kf0, qf[t][0], a);
        a = MFMA16(kf1, qf[t][1], a);
        u16x4 ev;
#pragma unroll
        for (int j = 0; j < 4; ++j) {
          float e = __expf(a[j]);
          lacc[t] += e;
          ev[j] = f2b(e);
        }
        *(u16x4*)(E + (((size_t)(b * 1024 + lq0 + la) * 16 + h) << 10) + lkg + fr * 16 + lg * 4) = ev;
      }
    }
  }
  // lsum: reduce across lg (lanes sharing q=la), store per-kc partial
#pragma unroll
  for (int t = 0; t < 2; ++t) {
    float s = lacc[t];
    s += __shfl_xor(s, 16);
    s += __shfl_xor(s, 32);
    if (lg == 0) lpart[kc * 32768 + (b * 16 + h0 + t) * 1024 + lq0 + la] = s;
  }
}

// ---------------- kernel 4: PV + transposed probs + gate ----------------
// Block (b,h,32q), 4 waves x 256 lk. linv merged in-block from lpart.
__global__ __launch_bounds__(256) void pv_k(
    const us* __restrict__ E, const us* __restrict__ Vt,
    const float* __restrict__ lpart, const float* __restrict__ G,
    float* __restrict__ outa, us* __restrict__ Ybf) {
  __shared__ char sm[49792];
  float* lv = (float*)(sm + 49664);
  int tid = threadIdx.x, lane = tid & 63, w = tid >> 6;
  int la = lane & 15, lg = lane >> 4;
  int bid = blockIdx.x;
  int g = bid >> 8, qt = (bid >> 3) & 31, xx = bid & 7;
  int bh = g * 8 + xx;
  int b = bh >> 4, h = bh & 15;
  int qb = qt * 32;
  if (tid < 32) {
    int r = bh * 1024 + qb + tid;
    float s = lpart[r] + lpart[32768 + r] + lpart[65536 + r] + lpart[98304 + r];
    lv[tid] = 1.f / s;
  }
  __syncthreads();
  char* pb = sm + w * 4096;  // [32 q][64 lk] bf16, chunk-XOR swizzle
  const us* Vh = Vt + (size_t)bh * 65536;
  f32x4 yacc[2][4] = {};
  int lkw = w * 256;

#pragma unroll 1
  for (int cc = 0; cc < 4; ++cc) {
    int lk0 = lkw + cc * 64;
    // stage E tile (reg-staged so dest can be swizzled)
#pragma unroll
    for (int it = 0; it < 4; ++it) {
      int ci = it * 64 + lane;
      int q = ci >> 3, c16 = ci & 7;
      short8 ev = *(const short8*)(E + (((size_t)(b * 1024 + qb + q) * 16 + h) << 10) + lk0 + c16 * 8);
      *(short8*)(pb + q * 128 + ((c16 * 16) ^ ((q & 7) << 4))) = ev;
    }
    // transposed probs: outa[b][lk][h][qb..qb+32)
#pragma unroll
    for (int it = 0; it < 8; ++it) {
      int idx = it * 64 + lane;
      int lkL = idx >> 3, q4 = idx & 7;
      f32x4 ov;
#pragma unroll
      for (int i = 0; i < 4; ++i) {
        int q = q4 * 4 + i;
        us e = *(const us*)(pb + q * 128 + ((2 * lkL) ^ ((q & 7) << 4)));
        ov[i] = b2f(e) * lv[q];
      }
      *(f32x4*)(outa + (((size_t)(b * 1024 + lk0 + lkL) * 16 + h) << 10) + qb + q4 * 4) = ov;
    }
    // PV
#pragma unroll
    for (int ks = 0; ks < 2; ++ks) {
      short8 pa[2];
#pragma unroll
      for (int qh = 0; qh < 2; ++qh) {
        int row = qh * 16 + la;
        pa[qh] = *(const short8*)(pb + row * 128 + ((ks * 64 + lg * 16) ^ ((row & 7) << 4)));
      }
#pragma unroll
      for (int ni = 0; ni < 4; ++ni) {
        short8 vf = *(const short8*)(Vh + (size_t)(ni * 16 + la) * 1024 + lk0 + ks * 32 + lg * 8);
        yacc[0][ni] = MFMA16(pa[0], vf, yacc[0][ni]);
        yacc[1][ni] = MFMA16(pa[1], vf, yacc[1][ni]);
      }
    }
  }

  // cross-wave O reduce + linv + gate
  float* red = (float*)(sm + 16384);  // [4 w][32 r][65]
#pragma unroll
  for (int qh = 0; qh < 2; ++qh)
#pragma unroll
    for (int ni = 0; ni < 4; ++ni)
#pragma unroll
      for (int j = 0; j < 4; ++j) {
        int r = qh * 16 + lg * 4 + j, c = ni * 16 + la;
        red[w * 2080 + r * 65 + c] = yacc[qh][ni][j];
      }
  __syncthreads();
#pragma unroll
  for (int rr = 0; rr < 8; ++rr) {
    int e = rr * 256 + tid;
    int r = e >> 6, c = e & 63;
    float s = red[r * 65 + c] + red[2080 + r * 65 + c] +
              red[4160 + r * 65 + c] + red[6240 + r * 65 + c];
    size_t gi = (((size_t)(b * 1024 + qb + r)) << 10) + h * 64 + c;
    Ybf[gi] = f2b(s * lv[r] * G[gi]);
  }
}

// ---------------- kernel 5: output projection ----------------
__global__ __launch_bounds__(256) void gemm_out_k(
    const us* __restrict__ Ybf, const us* __restrict__ Wobf,
    const float* __restrict__ bo, float* __restrict__ outy) {
  __shared__ char sm[32768];
  int bid = blockIdx.x;
  int swz = (bid & 7) * 16 + (bid >> 3);
  int tileM = swz >> 3, tileN = swz & 7;
  f32x4 acc[4][4] = {};
  gemm_main(Ybf, Wobf, tileM * 128, tileN * 128, acc, sm);
  int lane = threadIdx.x & 63, wid = threadIdx.x >> 6;
  int wr = wid >> 1, wc = wid & 1;
#pragma unroll
  for (int mi = 0; mi < 4; ++mi)
#pragma unroll
    for (int ni = 0; ni < 4; ++ni)
#pragma unroll
      for (int j = 0; j < 4; ++j) {
        int row = tileM * 128 + wr * 64 + mi * 16 + ((lane >> 4) << 2) + j;
        int col = tileN * 128 + wc * 64 + ni * 16 + (lane & 15);
        outy[(size_t)row * 1024 + col] = acc[mi][ni][j] + bo[col];
      }
}

extern "C" void kernel_launch(void* const* d_in, const int* in_sizes, int n_in,
                              void* d_out, int out_size, void* d_ws, size_t ws_size,
                              hipStream_t stream) {
  const float* x     = (const float*)d_in[0];
  const float* bias  = (const float*)d_in[1];
  const float* wproj = (const float*)d_in[2];
  const float* wo    = (const float*)d_in[3];
  const float* bo    = (const float*)d_in[4];
  const float* wg    = (const float*)d_in[5];
  const float* bg    = (const float*)d_in[6];
  float* outy = (float*)d_out;
  float* outa = outy + 2097152;  // y (2M f32), then probs (B,Lk,H,Lq) f32

  char* ws = (char*)d_ws;
  us*    Xbf  = (us*)(ws);
  us*    Wbf  = (us*)(ws + 4  * 1024 * 1024);
  us*    Wobf = (us*)(ws + 12 * 1024 * 1024);
  us*    Qb   = (us*)(ws + 14 * 1024 * 1024);
  us*    Kb   = (us*)(ws + 18 * 1024 * 1024);
  us*    Vt   = (us*)(ws + 22 * 1024 * 1024);
  float* G    = (float*)(ws + 26 * 1024 * 1024);
  us*    Ybf  = (us*)(ws + 34 * 1024 * 1024);
  float* lpart= (float*)(ws + (size_t)38 * 1024 * 1024);   // 512 KB
  us*    E    = (us*)   (ws + (size_t)40 * 1024 * 1024);   // 64 MB bf16
  if (ws_size < (size_t)104 * 1024 * 1024) return;

  prep_k<<<dim3(7168), dim3(256), 0, stream>>>(x, wproj, wg, wo, Xbf, Wbf, Wobf);
  gemm_qkvg_k<<<dim3(512), dim3(256), 0, stream>>>(Xbf, Wbf, Qb, Kb, Vt, G, bg);
  qke_k<<<dim3(512), dim3(512), 0, stream>>>(Qb, Kb, bias, E, lpart);
  pv_k<<<dim3(1024), dim3(256), 0, stream>>>(E, Vt, lpart, G, outa, Ybf);
  gemm_out_k<<<dim3(128), dim3(256), 0, stream>>>(Ybf, Wobf, bo, outy);
}

// Round 10
// 200.471 us; speedup vs baseline: 1.3247x; 1.0012x over previous
//
#include <hip/hip_runtime.h>
#include <hip/hip_bf16.h>
#include <stdint.h>

typedef __attribute__((ext_vector_type(4))) float f32x4;
typedef __attribute__((ext_vector_type(8))) short short8;
typedef __attribute__((ext_vector_type(4))) unsigned short u16x4;
typedef unsigned short us;

#define DEV __device__ __forceinline__
#define MFMA16(a, b, c) __builtin_amdgcn_mfma_f32_16x16x32_bf16(a, b, c, 0, 0, 0)

DEV us f2b(float x) {
  union { float f; uint32_t u; } c; c.f = x;
  uint32_t r = (c.u + 0x7fffu + ((c.u >> 16) & 1u)) >> 16;
  return (us)r;
}
DEV float b2f(us x) {
  union { uint32_t u; float f; } c; c.u = ((uint32_t)x) << 16;
  return c.f;
}

DEV void gload_lds16(const void* g, void* l) {
  __builtin_amdgcn_global_load_lds((const __attribute__((address_space(1))) void*)g,
                                   (__attribute__((address_space(3))) void*)l, 16, 0, 0);
}

// ---------------- kernel 1: fp32 -> bf16 conversions ----------------
__global__ __launch_bounds__(256) void prep_k(
    const float* __restrict__ x, const float* __restrict__ wproj,
    const float* __restrict__ wg, const float* __restrict__ wo,
    us* __restrict__ Xbf, us* __restrict__ Wbf, us* __restrict__ Wobf) {
  int i = blockIdx.x * 256 + threadIdx.x;
  const float* src; us* dst;
  if (i < 524288)               { src = x     + (size_t)i * 4;                  dst = Xbf + (size_t)i * 4; }
  else if (i < 524288 + 786432) { int j = i - 524288;            src = wproj + (size_t)j * 4; dst = Wbf + (size_t)j * 4; }
  else if (i < 524288 + 786432 + 262144) { int j = i - (524288 + 786432); src = wg + (size_t)j * 4; dst = Wbf + 3145728 + (size_t)j * 4; }
  else                          { int j = i - (524288 + 786432 + 262144); src = wo + (size_t)j * 4; dst = Wobf + (size_t)j * 4; }
  f32x4 v = *(const f32x4*)src;
  u16x4 o; o.x = f2b(v.x); o.y = f2b(v.y); o.z = f2b(v.z); o.w = f2b(v.w);
  *(u16x4*)dst = o;
}

// ---------------- shared GEMM core (m97-style, 128x128) ----------------
DEV void gemm_stage(char* sm, const us* A, const us* Bw,
                    int tileMrow, int tileNrow, int buf, int kt, int lane, int wid) {
  const char* gA = (const char*)A;
  const char* gB = (const char*)Bw;
#pragma unroll
  for (int i = 0; i < 2; ++i) {
    int c = wid * 2 + i;
    int off = c * 1024 + lane * 16;
    int r = off >> 6, cb = off & 63;
    gload_lds16(gA + ((size_t)(tileMrow + r) * 2048) + kt * 64 + cb, sm + buf * 8192 + c * 1024);
    gload_lds16(gB + ((size_t)(tileNrow + r) * 2048) + kt * 64 + cb, sm + 16384 + buf * 8192 + c * 1024);
  }
}

DEV void gemm_main(const us* A, const us* Bw,
                   int tileMrow, int tileNrow, f32x4 acc[4][4], char* sm) {
  int tid = threadIdx.x, lane = tid & 63, wid = tid >> 6;
  int wr = wid >> 1, wc = wid & 1;
  gemm_stage(sm, A, Bw, tileMrow, tileNrow, 0, 0, lane, wid);
  for (int kt = 0; kt < 32; ++kt) {
    __syncthreads();
    if (kt < 31) gemm_stage(sm, A, Bw, tileMrow, tileNrow, (kt + 1) & 1, kt + 1, lane, wid);
    int ab = (kt & 1) * 8192;
    int rb = (lane & 15) * 64 + ((lane >> 4) * 16);
    short8 af[4], bf[4];
#pragma unroll
    for (int mi = 0; mi < 4; ++mi)
      af[mi] = *(const short8*)(sm + ab + (wr * 64 + mi * 16) * 64 + rb);
#pragma unroll
    for (int ni = 0; ni < 4; ++ni)
      bf[ni] = *(const short8*)(sm + 16384 + ab + (wc * 64 + ni * 16) * 64 + rb);
#pragma unroll
    for (int mi = 0; mi < 4; ++mi)
#pragma unroll
      for (int ni = 0; ni < 4; ++ni)
        acc[mi][ni] = MFMA16(af[mi], bf[ni], acc[mi][ni]);
  }
}

// ---------------- kernel 2: QKV+gate projection ----------------
__global__ __launch_bounds__(256) void gemm_qkvg_k(
    const us* __restrict__ Xbf, const us* __restrict__ Wbf,
    us* __restrict__ Qb, us* __restrict__ Kb, us* __restrict__ Vt,
    float* __restrict__ G, const float* __restrict__ bg) {
  __shared__ char sm[32768];
  int bid = blockIdx.x;
  int swz = (bid & 7) * 64 + (bid >> 3);
  int tileM = swz >> 5, tileN = swz & 31;
  f32x4 acc[4][4] = {};
  gemm_main(Xbf, Wbf, tileM * 128, tileN * 128, acc, sm);
  int lane = threadIdx.x & 63, wid = threadIdx.x >> 6;
  int wr = wid >> 1, wc = wid & 1;
#pragma unroll
  for (int mi = 0; mi < 4; ++mi)
#pragma unroll
    for (int ni = 0; ni < 4; ++ni)
#pragma unroll
      for (int j = 0; j < 4; ++j) {
        int row = tileM * 128 + wr * 64 + mi * 16 + ((lane >> 4) << 2) + j;
        int col = tileN * 128 + wc * 64 + ni * 16 + (lane & 15);
        float v = acc[mi][ni][j];
        int b = row >> 10, l = row & 1023;
        if (col < 3072) {
          int h = col / 192, r = col - h * 192;
          size_t base = ((size_t)(b * 16 + h) * 1024 + l) * 64;
          if (r < 64)        Qb[base + r] = f2b(v * 0.125f);
          else if (r < 128)  Kb[base + (r - 64)] = f2b(v);
          else               Vt[((size_t)(b * 16 + h) * 64 + (r - 128)) * 1024 + l] = f2b(v);
        } else {
          int e = col - 3072;
          float s = v + bg[e];
          G[(size_t)row * 1024 + e] = 1.f / (1.f + __expf(-s));
        }
      }
}

// ---------------- kernel 3: fused QK^T + bias + exp -> E, lsum partials ----------------
// Block (b, qt:16q, kc:256lk, hg:8 heads). 8 waves, ONE head per wave.
// 18.4KB LDS -> 4 blocks/CU (32 waves) for latency hiding. hg-siblings are
// 8 apart in bid -> same XCD -> bias half-lines dedup in L2.
__global__ __launch_bounds__(512, 8) void qke_k(
    const us* __restrict__ Qb, const us* __restrict__ Kb,
    const float* __restrict__ bias, us* __restrict__ E,
    float* __restrict__ lpart) {
  __shared__ float bt[2][8][16][36];   // [buf][h_local][q][lk32 + pad4]
  int tid = threadIdx.x, lane = tid & 63, w = tid >> 6;
  int la = lane & 15, lg = lane >> 4;
  int bid = blockIdx.x;
  // bid = qt*16 + hg*8 + (b*4+kc): xcd = bid%8 = b*4+kc for all qt, both hg
  int b = (bid & 7) >> 2, kc = bid & 3;
  int hg = (bid >> 3) & 1, qt = bid >> 4;
  int lq0 = qt * 16, lk00 = kc * 256;
  int h = hg * 8 + w;                  // this wave's head
  int hh = w;                          // local head index 0..7

  short8 qf[2];
  {
    size_t bh = (size_t)(b * 16 + h);
#pragma unroll
    for (int ks = 0; ks < 2; ++ks)
      qf[ks] = *(const short8*)(Qb + bh * 65536 + (size_t)(lq0 + la) * 64 + ks * 32 + lg * 8);
  }
  const us* Kh = Kb + (size_t)(b * 16 + h) * 65536;
  const float* bsrc = bias + ((size_t)b << 24) + ((size_t)lq0 << 14) + hg * 8;

  // stage chunk 0: [16q][32lk][8h] fp32 = 16KB, 2 f32x4/thread
#pragma unroll
  for (int i = 0; i < 2; ++i) {
    int f = tid + i * 512;
    int h4 = f & 1, lk = (f >> 1) & 31, q = f >> 6;
    f32x4 v = *(const f32x4*)(bsrc + ((size_t)q << 14) + ((size_t)(lk00 + lk) << 4) + h4 * 4);
#pragma unroll
    for (int e = 0; e < 4; ++e) {
      int hl = h4 * 4 + e;
      bt[0][hl][q][lk ^ (hl << 2)] = v[e];
    }
  }

  float lacc = 0.f;
#pragma unroll 1
  for (int sc = 0; sc < 8; ++sc) {
    __syncthreads();
    if (sc < 7) {
      int lkg2 = lk00 + (sc + 1) * 32;
      int nb = (sc + 1) & 1;
#pragma unroll
      for (int i = 0; i < 2; ++i) {
        int f = tid + i * 512;
        int h4 = f & 1, lk = (f >> 1) & 31, q = f >> 6;
        f32x4 v = *(const f32x4*)(bsrc + ((size_t)q << 14) + ((size_t)(lkg2 + lk) << 4) + h4 * 4);
#pragma unroll
        for (int e = 0; e < 4; ++e) {
          int hl = h4 * 4 + e;
          bt[nb][hl][q][lk ^ (hl << 2)] = v[e];
        }
      }
    }
    int cb = sc & 1;
    int lkg = lk00 + sc * 32;
#pragma unroll
    for (int fr = 0; fr < 2; ++fr) {
      const us* kr = Kh + (size_t)(lkg + fr * 16 + la) * 64 + lg * 8;
      short8 kf0 = *(const short8*)kr;
      short8 kf1 = *(const short8*)(kr + 32);
      int lkb = (fr * 16 + lg * 4) ^ (hh << 2);
      f32x4 a = *(const f32x4*)&bt[cb][hh][la][lkb];
      a = MFMA16(kf0, qf[0], a);
      a = MFMA16(kf1, qf[1], a);
      u16x4 ev;
#pragma unroll
      for (int j = 0; j < 4; ++j) {
        float e = __expf(a[j]);
        lacc += e;
        ev[j] = f2b(e);
      }
      *(u16x4*)(E + (((size_t)(b * 1024 + lq0 + la) * 16 + h) << 10) + lkg + fr * 16 + lg * 4) = ev;
    }
  }
  // lsum: reduce across lg (lanes sharing q=la), store per-kc partial
  {
    float s = lacc;
    s += __shfl_xor(s, 16);
    s += __shfl_xor(s, 32);
    if (lg == 0) lpart[kc * 32768 + (b * 16 + h) * 1024 + lq0 + la] = s;
  }
}

// ---------------- kernel 4: PV + transposed probs + gate ----------------
// Block (b,h,32q), 4 waves x 256 lk. linv merged in-block from lpart.
__global__ __launch_bounds__(256) void pv_k(
    const us* __restrict__ E, const us* __restrict__ Vt,
    const float* __restrict__ lpart, const float* __restrict__ G,
    float* __restrict__ outa, us* __restrict__ Ybf) {
  __shared__ char sm[49792];
  float* lv = (float*)(sm + 49664);
  int tid = threadIdx.x, lane = tid & 63, w = tid >> 6;
  int la = lane & 15, lg = lane >> 4;
  int bid = blockIdx.x;
  int g = bid >> 8, qt = (bid >> 3) & 31, xx = bid & 7;
  int bh = g * 8 + xx;
  int b = bh >> 4, h = bh & 15;
  int qb = qt * 32;
  if (tid < 32) {
    int r = bh * 1024 + qb + tid;
    float s = lpart[r] + lpart[32768 + r] + lpart[65536 + r] + lpart[98304 + r];
    lv[tid] = 1.f / s;
  }
  __syncthreads();
  char* pb = sm + w * 4096;  // [32 q][64 lk] bf16, chunk-XOR swizzle
  const us* Vh = Vt + (size_t)bh * 65536;
  f32x4 yacc[2][4] = {};
  int lkw = w * 256;

#pragma unroll 1
  for (int cc = 0; cc < 4; ++cc) {
    int lk0 = lkw + cc * 64;
    // stage E tile (reg-staged so dest can be swizzled)
#pragma unroll
    for (int it = 0; it < 4; ++it) {
      int ci = it * 64 + lane;
      int q = ci >> 3, c16 = ci & 7;
      short8 ev = *(const short8*)(E + (((size_t)(b * 1024 + qb + q) * 16 + h) << 10) + lk0 + c16 * 8);
      *(short8*)(pb + q * 128 + ((c16 * 16) ^ ((q & 7) << 4))) = ev;
    }
    // transposed probs: outa[b][lk][h][qb..qb+32)
#pragma unroll
    for (int it = 0; it < 8; ++it) {
      int idx = it * 64 + lane;
      int lkL = idx >> 3, q4 = idx & 7;
      f32x4 ov;
#pragma unroll
      for (int i = 0; i < 4; ++i) {
        int q = q4 * 4 + i;
        us e = *(const us*)(pb + q * 128 + ((2 * lkL) ^ ((q & 7) << 4)));
        ov[i] = b2f(e) * lv[q];
      }
      *(f32x4*)(outa + (((size_t)(b * 1024 + lk0 + lkL) * 16 + h) << 10) + qb + q4 * 4) = ov;
    }
    // PV
#pragma unroll
    for (int ks = 0; ks < 2; ++ks) {
      short8 pa[2];
#pragma unroll
      for (int qh = 0; qh < 2; ++qh) {
        int row = qh * 16 + la;
        pa[qh] = *(const short8*)(pb + row * 128 + ((ks * 64 + lg * 16) ^ ((row & 7) << 4)));
      }
#pragma unroll
      for (int ni = 0; ni < 4; ++ni) {
        short8 vf = *(const short8*)(Vh + (size_t)(ni * 16 + la) * 1024 + lk0 + ks * 32 + lg * 8);
        yacc[0][ni] = MFMA16(pa[0], vf, yacc[0][ni]);
        yacc[1][ni] = MFMA16(pa[1], vf, yacc[1][ni]);
      }
    }
  }

  // cross-wave O reduce + linv + gate
  float* red = (float*)(sm + 16384);  // [4 w][32 r][65]
#pragma unroll
  for (int qh = 0; qh < 2; ++qh)
#pragma unroll
    for (int ni = 0; ni < 4; ++ni)
#pragma unroll
      for (int j = 0; j < 4; ++j) {
        int r = qh * 16 + lg * 4 + j, c = ni * 16 + la;
        red[w * 2080 + r * 65 + c] = yacc[qh][ni][j];
      }
  __syncthreads();
#pragma unroll
  for (int rr = 0; rr < 8; ++rr) {
    int e = rr * 256 + tid;
    int r = e >> 6, c = e & 63;
    float s = red[r * 65 + c] + red[2080 + r * 65 + c] +
              red[4160 + r * 65 + c] + red[6240 + r * 65 + c];
    size_t gi = (((size_t)(b * 1024 + qb + r)) << 10) + h * 64 + c;
    Ybf[gi] = f2b(s * lv[r] * G[gi]);
  }
}

// ---------------- kernel 5: output projection ----------------
__global__ __launch_bounds__(256) void gemm_out_k(
    const us* __restrict__ Ybf, const us* __restrict__ Wobf,
    const float* __restrict__ bo, float* __restrict__ outy) {
  __shared__ char sm[32768];
  int bid = blockIdx.x;
  int swz = (bid & 7) * 16 + (bid >> 3);
  int tileM = swz >> 3, tileN = swz & 7;
  f32x4 acc[4][4] = {};
  gemm_main(Ybf, Wobf, tileM * 128, tileN * 128, acc, sm);
  int lane = threadIdx.x & 63, wid = threadIdx.x >> 6;
  int wr = wid >> 1, wc = wid & 1;
#pragma unroll
  for (int mi = 0; mi < 4; ++mi)
#pragma unroll
    for (int ni = 0; ni < 4; ++ni)
#pragma unroll
      for (int j = 0; j < 4; ++j) {
        int row = tileM * 128 + wr * 64 + mi * 16 + ((lane >> 4) << 2) + j;
        int col = tileN * 128 + wc * 64 + ni * 16 + (lane & 15);
        outy[(size_t)row * 1024 + col] = acc[mi][ni][j] + bo[col];
      }
}

extern "C" void kernel_launch(void* const* d_in, const int* in_sizes, int n_in,
                              void* d_out, int out_size, void* d_ws, size_t ws_size,
                              hipStream_t stream) {
  const float* x     = (const float*)d_in[0];
  const float* bias  = (const float*)d_in[1];
  const float* wproj = (const float*)d_in[2];
  const float* wo    = (const float*)d_in[3];
  const float* bo    = (const float*)d_in[4];
  const float* wg    = (const float*)d_in[5];
  const float* bg    = (const float*)d_in[6];
  float* outy = (float*)d_out;
  float* outa = outy + 2097152;  // y (2M f32), then probs (B,Lk,H,Lq) f32

  char* ws = (char*)d_ws;
  us*    Xbf  = (us*)(ws);
  us*    Wbf  = (us*)(ws + 4  * 1024 * 1024);
  us*    Wobf = (us*)(ws + 12 * 1024 * 1024);
  us*    Qb   = (us*)(ws + 14 * 1024 * 1024);
  us*    Kb   = (us*)(ws + 18 * 1024 * 1024);
  us*    Vt   = (us*)(ws + 22 * 1024 * 1024);
  float* G    = (float*)(ws + 26 * 1024 * 1024);
  us*    Ybf  = (us*)(ws + 34 * 1024 * 1024);
  float* lpart= (float*)(ws + (size_t)38 * 1024 * 1024);   // 512 KB
  us*    E    = (us*)   (ws + (size_t)40 * 1024 * 1024);   // 64 MB bf16
  if (ws_size < (size_t)104 * 1024 * 1024) return;

  prep_k<<<dim3(7168), dim3(256), 0, stream>>>(x, wproj, wg, wo, Xbf, Wbf, Wobf);
  gemm_qkvg_k<<<dim3(512), dim3(256), 0, stream>>>(Xbf, Wbf, Qb, Kb, Vt, G, bg);
  qke_k<<<dim3(1024), dim3(512), 0, stream>>>(Qb, Kb, bias, E, lpart);
  pv_k<<<dim3(1024), dim3(256), 0, stream>>>(E, Vt, lpart, G, outa, Ybf);
  gemm_out_k<<<dim3(128), dim3(256), 0, stream>>>(Ybf, Wobf, bo, outy);
}

// Round 11
// 194.912 us; speedup vs baseline: 1.3625x; 1.0285x over previous
//
#include <hip/hip_runtime.h>
#include <hip/hip_bf16.h>
#include <stdint.h>

typedef __attribute__((ext_vector_type(4))) float f32x4;
typedef __attribute__((ext_vector_type(8))) short short8;
typedef __attribute__((ext_vector_type(4))) unsigned short u16x4;
typedef unsigned short us;

#define DEV __device__ __forceinline__
#define MFMA16(a, b, c) __builtin_amdgcn_mfma_f32_16x16x32_bf16(a, b, c, 0, 0, 0)

DEV us f2b(float x) {
  union { float f; uint32_t u; } c; c.f = x;
  uint32_t r = (c.u + 0x7fffu + ((c.u >> 16) & 1u)) >> 16;
  return (us)r;
}
DEV float b2f(us x) {
  union { uint32_t u; float f; } c; c.u = ((uint32_t)x) << 16;
  return c.f;
}

DEV void gload_lds16(const void* g, void* l) {
  __builtin_amdgcn_global_load_lds((const __attribute__((address_space(1))) void*)g,
                                   (__attribute__((address_space(3))) void*)l, 16, 0, 0);
}

// ---------------- kernel 1: fp32 -> bf16 conversions ----------------
__global__ __launch_bounds__(256) void prep_k(
    const float* __restrict__ x, const float* __restrict__ wproj,
    const float* __restrict__ wg, const float* __restrict__ wo,
    us* __restrict__ Xbf, us* __restrict__ Wbf, us* __restrict__ Wobf) {
  int i = blockIdx.x * 256 + threadIdx.x;
  const float* src; us* dst;
  if (i < 524288)               { src = x     + (size_t)i * 4;                  dst = Xbf + (size_t)i * 4; }
  else if (i < 524288 + 786432) { int j = i - 524288;            src = wproj + (size_t)j * 4; dst = Wbf + (size_t)j * 4; }
  else if (i < 524288 + 786432 + 262144) { int j = i - (524288 + 786432); src = wg + (size_t)j * 4; dst = Wbf + 3145728 + (size_t)j * 4; }
  else                          { int j = i - (524288 + 786432 + 262144); src = wo + (size_t)j * 4; dst = Wobf + (size_t)j * 4; }
  f32x4 v = *(const f32x4*)src;
  u16x4 o; o.x = f2b(v.x); o.y = f2b(v.y); o.z = f2b(v.z); o.w = f2b(v.w);
  *(u16x4*)dst = o;
}

// ---------------- shared GEMM core (m97-style, 128x128) ----------------
DEV void gemm_stage(char* sm, const us* A, const us* Bw,
                    int tileMrow, int tileNrow, int buf, int kt, int lane, int wid) {
  const char* gA = (const char*)A;
  const char* gB = (const char*)Bw;
#pragma unroll
  for (int i = 0; i < 2; ++i) {
    int c = wid * 2 + i;
    int off = c * 1024 + lane * 16;
    int r = off >> 6, cb = off & 63;
    gload_lds16(gA + ((size_t)(tileMrow + r) * 2048) + kt * 64 + cb, sm + buf * 8192 + c * 1024);
    gload_lds16(gB + ((size_t)(tileNrow + r) * 2048) + kt * 64 + cb, sm + 16384 + buf * 8192 + c * 1024);
  }
}

DEV void gemm_main(const us* A, const us* Bw,
                   int tileMrow, int tileNrow, f32x4 acc[4][4], char* sm) {
  int tid = threadIdx.x, lane = tid & 63, wid = tid >> 6;
  int wr = wid >> 1, wc = wid & 1;
  gemm_stage(sm, A, Bw, tileMrow, tileNrow, 0, 0, lane, wid);
  for (int kt = 0; kt < 32; ++kt) {
    __syncthreads();
    if (kt < 31) gemm_stage(sm, A, Bw, tileMrow, tileNrow, (kt + 1) & 1, kt + 1, lane, wid);
    int ab = (kt & 1) * 8192;
    int rb = (lane & 15) * 64 + ((lane >> 4) * 16);
    short8 af[4], bf[4];
#pragma unroll
    for (int mi = 0; mi < 4; ++mi)
      af[mi] = *(const short8*)(sm + ab + (wr * 64 + mi * 16) * 64 + rb);
#pragma unroll
    for (int ni = 0; ni < 4; ++ni)
      bf[ni] = *(const short8*)(sm + 16384 + ab + (wc * 64 + ni * 16) * 64 + rb);
#pragma unroll
    for (int mi = 0; mi < 4; ++mi)
#pragma unroll
      for (int ni = 0; ni < 4; ++ni)
        acc[mi][ni] = MFMA16(af[mi], bf[ni], acc[mi][ni]);
  }
}

// ---------------- kernel 2: QKV+gate projection ----------------
__global__ __launch_bounds__(256) void gemm_qkvg_k(
    const us* __restrict__ Xbf, const us* __restrict__ Wbf,
    us* __restrict__ Qb, us* __restrict__ Kb, us* __restrict__ Vt,
    float* __restrict__ G, const float* __restrict__ bg) {
  __shared__ char sm[32768];
  int bid = blockIdx.x;
  int swz = (bid & 7) * 64 + (bid >> 3);
  int tileM = swz >> 5, tileN = swz & 31;
  f32x4 acc[4][4] = {};
  gemm_main(Xbf, Wbf, tileM * 128, tileN * 128, acc, sm);
  int lane = threadIdx.x & 63, wid = threadIdx.x >> 6;
  int wr = wid >> 1, wc = wid & 1;
#pragma unroll
  for (int mi = 0; mi < 4; ++mi)
#pragma unroll
    for (int ni = 0; ni < 4; ++ni)
#pragma unroll
      for (int j = 0; j < 4; ++j) {
        int row = tileM * 128 + wr * 64 + mi * 16 + ((lane >> 4) << 2) + j;
        int col = tileN * 128 + wc * 64 + ni * 16 + (lane & 15);
        float v = acc[mi][ni][j];
        int b = row >> 10, l = row & 1023;
        if (col < 3072) {
          int h = col / 192, r = col - h * 192;
          size_t base = ((size_t)(b * 16 + h) * 1024 + l) * 64;
          if (r < 64)        Qb[base + r] = f2b(v * 0.125f);
          else if (r < 128)  Kb[base + (r - 64)] = f2b(v);
          else               Vt[((size_t)(b * 16 + h) * 64 + (r - 128)) * 1024 + l] = f2b(v);
        } else {
          int e = col - 3072;
          float s = v + bg[e];
          G[(size_t)row * 1024 + e] = 1.f / (1.f + __expf(-s));
        }
      }
}

// ---------------- kernel 3: fused QK^T + bias + exp -> E, lsum partials ----------------
// Block (b, qt:16q, kc:256lk, hg:8 heads); 8 waves, one head/wave. NEW issue
// structure: bias staged in 128-lk halves (8-deep load queue), double-buffered,
// only TWO barriers per block; half-1 loads issued before half-0 compute
// (latency hidden under 8 fr of MFMA+exp); no store-drains inside compute.
__global__ __launch_bounds__(512, 4) void qke_k(
    const us* __restrict__ Qb, const us* __restrict__ Kb,
    const float* __restrict__ bias, us* __restrict__ E,
    float* __restrict__ lpart) {
  __shared__ float bt[2][4][8][16][36];   // [buf][chunk32][hl][q][slk^ pad36]
  int tid = threadIdx.x, lane = tid & 63, w = tid >> 6;
  int la = lane & 15, lg = lane >> 4;
  int bid = blockIdx.x;
  int b = (bid & 7) >> 2, kc = bid & 3;
  int hg = (bid >> 3) & 1, qt = bid >> 4;
  int lq0 = qt * 16, lk00 = kc * 256;
  int h = hg * 8 + w, hh = w;

  short8 qf[2];
  {
    size_t bh = (size_t)(b * 16 + h);
#pragma unroll
    for (int ks = 0; ks < 2; ++ks)
      qf[ks] = *(const short8*)(Qb + bh * 65536 + (size_t)(lq0 + la) * 64 + ks * 32 + lg * 8);
  }
  const us* Kh = Kb + (size_t)(b * 16 + h) * 65536;
  const float* bsrc = bias + ((size_t)b << 24) + ((size_t)lq0 << 14) + hg * 8;
  us* Erow = E + (((size_t)(b * 1024 + lq0 + la) * 16 + h) << 10);

  f32x4 vv[8];
  // ---- stage half 0: 8 loads issued back-to-back, then writes ----
#pragma unroll
  for (int i = 0; i < 8; ++i) {
    int f = i * 512 + tid;
    int h4 = f & 1, lk = (f >> 1) & 127, q = f >> 8;
    vv[i] = *(const f32x4*)(bsrc + ((size_t)q << 14) + ((size_t)(lk00 + lk) << 4) + h4 * 4);
  }
#pragma unroll
  for (int i = 0; i < 8; ++i) {
    int f = i * 512 + tid;
    int h4 = f & 1, lk = (f >> 1) & 127, q = f >> 8;
    int c = lk >> 5, slk = lk & 31;
#pragma unroll
    for (int e = 0; e < 4; ++e) {
      int hl = h4 * 4 + e;
      bt[0][c][hl][q][slk ^ (hl << 2)] = vv[i][e];
    }
  }
  __syncthreads();   // barrier 1: half-0 tile ready

  float lacc = 0.f;
  // ---- issue half-1 loads (latency hides under half-0 compute) ----
#pragma unroll
  for (int i = 0; i < 8; ++i) {
    int f = i * 512 + tid;
    int h4 = f & 1, lk = (f >> 1) & 127, q = f >> 8;
    vv[i] = *(const f32x4*)(bsrc + ((size_t)q << 14) + ((size_t)(lk00 + 128 + lk) << 4) + h4 * 4);
  }
  // ---- compute half 0: 8 fr, no barriers ----
#pragma unroll
  for (int fr = 0; fr < 8; ++fr) {
    int c = fr >> 1;
    const us* kr = Kh + (size_t)(lk00 + fr * 16 + la) * 64 + lg * 8;
    short8 kf0 = *(const short8*)kr;
    short8 kf1 = *(const short8*)(kr + 32);
    int lkb = ((fr & 1) * 16 + lg * 4) ^ (hh << 2);
    f32x4 a = *(const f32x4*)&bt[0][c][hh][la][lkb];
    a = MFMA16(kf0, qf[0], a);
    a = MFMA16(kf1, qf[1], a);
    u16x4 ev;
#pragma unroll
    for (int j = 0; j < 4; ++j) {
      float e = __expf(a[j]);
      lacc += e;
      ev[j] = f2b(e);
    }
    *(u16x4*)(Erow + lk00 + fr * 16 + lg * 4) = ev;
  }
  // ---- write half-1 tile (buf 1; half-0 reads unaffected), barrier 2 ----
#pragma unroll
  for (int i = 0; i < 8; ++i) {
    int f = i * 512 + tid;
    int h4 = f & 1, lk = (f >> 1) & 127, q = f >> 8;
    int c = lk >> 5, slk = lk & 31;
#pragma unroll
    for (int e = 0; e < 4; ++e) {
      int hl = h4 * 4 + e;
      bt[1][c][hl][q][slk ^ (hl << 2)] = vv[i][e];
    }
  }
  __syncthreads();
  // ---- compute half 1 ----
#pragma unroll
  for (int fr = 0; fr < 8; ++fr) {
    int c = fr >> 1;
    const us* kr = Kh + (size_t)(lk00 + 128 + fr * 16 + la) * 64 + lg * 8;
    short8 kf0 = *(const short8*)kr;
    short8 kf1 = *(const short8*)(kr + 32);
    int lkb = ((fr & 1) * 16 + lg * 4) ^ (hh << 2);
    f32x4 a = *(const f32x4*)&bt[1][c][hh][la][lkb];
    a = MFMA16(kf0, qf[0], a);
    a = MFMA16(kf1, qf[1], a);
    u16x4 ev;
#pragma unroll
    for (int j = 0; j < 4; ++j) {
      float e = __expf(a[j]);
      lacc += e;
      ev[j] = f2b(e);
    }
    *(u16x4*)(Erow + lk00 + 128 + fr * 16 + lg * 4) = ev;
  }
  // ---- lsum: reduce across lg (lanes sharing q=la), per-kc partial ----
  {
    float s = lacc;
    s += __shfl_xor(s, 16);
    s += __shfl_xor(s, 32);
    if (lg == 0) lpart[kc * 32768 + (b * 16 + h) * 1024 + lq0 + la] = s;
  }
}

// ---------------- kernel 4: PV + transposed probs + gate ----------------
// Block (b,h,32q), 4 waves x 256 lk. linv merged in-block from lpart.
__global__ __launch_bounds__(256) void pv_k(
    const us* __restrict__ E, const us* __restrict__ Vt,
    const float* __restrict__ lpart, const float* __restrict__ G,
    float* __restrict__ outa, us* __restrict__ Ybf) {
  __shared__ char sm[49792];
  float* lv = (float*)(sm + 49664);
  int tid = threadIdx.x, lane = tid & 63, w = tid >> 6;
  int la = lane & 15, lg = lane >> 4;
  int bid = blockIdx.x;
  int g = bid >> 8, qt = (bid >> 3) & 31, xx = bid & 7;
  int bh = g * 8 + xx;
  int b = bh >> 4, h = bh & 15;
  int qb = qt * 32;
  if (tid < 32) {
    int r = bh * 1024 + qb + tid;
    float s = lpart[r] + lpart[32768 + r] + lpart[65536 + r] + lpart[98304 + r];
    lv[tid] = 1.f / s;
  }
  __syncthreads();
  char* pb = sm + w * 4096;  // [32 q][64 lk] bf16, chunk-XOR swizzle
  const us* Vh = Vt + (size_t)bh * 65536;
  f32x4 yacc[2][4] = {};
  int lkw = w * 256;

#pragma unroll 1
  for (int cc = 0; cc < 4; ++cc) {
    int lk0 = lkw + cc * 64;
    // stage E tile (reg-staged so dest can be swizzled)
#pragma unroll
    for (int it = 0; it < 4; ++it) {
      int ci = it * 64 + lane;
      int q = ci >> 3, c16 = ci & 7;
      short8 ev = *(const short8*)(E + (((size_t)(b * 1024 + qb + q) * 16 + h) << 10) + lk0 + c16 * 8);
      *(short8*)(pb + q * 128 + ((c16 * 16) ^ ((q & 7) << 4))) = ev;
    }
    // transposed probs: outa[b][lk][h][qb..qb+32)
#pragma unroll
    for (int it = 0; it < 8; ++it) {
      int idx = it * 64 + lane;
      int lkL = idx >> 3, q4 = idx & 7;
      f32x4 ov;
#pragma unroll
      for (int i = 0; i < 4; ++i) {
        int q = q4 * 4 + i;
        us e = *(const us*)(pb + q * 128 + ((2 * lkL) ^ ((q & 7) << 4)));
        ov[i] = b2f(e) * lv[q];
      }
      *(f32x4*)(outa + (((size_t)(b * 1024 + lk0 + lkL) * 16 + h) << 10) + qb + q4 * 4) = ov;
    }
    // PV
#pragma unroll
    for (int ks = 0; ks < 2; ++ks) {
      short8 pa[2];
#pragma unroll
      for (int qh = 0; qh < 2; ++qh) {
        int row = qh * 16 + la;
        pa[qh] = *(const short8*)(pb + row * 128 + ((ks * 64 + lg * 16) ^ ((row & 7) << 4)));
      }
#pragma unroll
      for (int ni = 0; ni < 4; ++ni) {
        short8 vf = *(const short8*)(Vh + (size_t)(ni * 16 + la) * 1024 + lk0 + ks * 32 + lg * 8);
        yacc[0][ni] = MFMA16(pa[0], vf, yacc[0][ni]);
        yacc[1][ni] = MFMA16(pa[1], vf, yacc[1][ni]);
      }
    }
  }

  // cross-wave O reduce + linv + gate
  float* red = (float*)(sm + 16384);  // [4 w][32 r][65]
#pragma unroll
  for (int qh = 0; qh < 2; ++qh)
#pragma unroll
    for (int ni = 0; ni < 4; ++ni)
#pragma unroll
      for (int j = 0; j < 4; ++j) {
        int r = qh * 16 + lg * 4 + j, c = ni * 16 + la;
        red[w * 2080 + r * 65 + c] = yacc[qh][ni][j];
      }
  __syncthreads();
#pragma unroll
  for (int rr = 0; rr < 8; ++rr) {
    int e = rr * 256 + tid;
    int r = e >> 6, c = e & 63;
    float s = red[r * 65 + c] + red[2080 + r * 65 + c] +
              red[4160 + r * 65 + c] + red[6240 + r * 65 + c];
    size_t gi = (((size_t)(b * 1024 + qb + r)) << 10) + h * 64 + c;
    Ybf[gi] = f2b(s * lv[r] * G[gi]);
  }
}

// ---------------- kernel 5: output projection ----------------
__global__ __launch_bounds__(256) void gemm_out_k(
    const us* __restrict__ Ybf, const us* __restrict__ Wobf,
    const float* __restrict__ bo, float* __restrict__ outy) {
  __shared__ char sm[32768];
  int bid = blockIdx.x;
  int swz = (bid & 7) * 16 + (bid >> 3);
  int tileM = swz >> 3, tileN = swz & 7;
  f32x4 acc[4][4] = {};
  gemm_main(Ybf, Wobf, tileM * 128, tileN * 128, acc, sm);
  int lane = threadIdx.x & 63, wid = threadIdx.x >> 6;
  int wr = wid >> 1, wc = wid & 1;
#pragma unroll
  for (int mi = 0; mi < 4; ++mi)
#pragma unroll
    for (int ni = 0; ni < 4; ++ni)
#pragma unroll
      for (int j = 0; j < 4; ++j) {
        int row = tileM * 128 + wr * 64 + mi * 16 + ((lane >> 4) << 2) + j;
        int col = tileN * 128 + wc * 64 + ni * 16 + (lane & 15);
        outy[(size_t)row * 1024 + col] = acc[mi][ni][j] + bo[col];
      }
}

extern "C" void kernel_launch(void* const* d_in, const int* in_sizes, int n_in,
                              void* d_out, int out_size, void* d_ws, size_t ws_size,
                              hipStream_t stream) {
  const float* x     = (const float*)d_in[0];
  const float* bias  = (const float*)d_in[1];
  const float* wproj = (const float*)d_in[2];
  const float* wo    = (const float*)d_in[3];
  const float* bo    = (const float*)d_in[4];
  const float* wg    = (const float*)d_in[5];
  const float* bg    = (const float*)d_in[6];
  float* outy = (float*)d_out;
  float* outa = outy + 2097152;  // y (2M f32), then probs (B,Lk,H,Lq) f32

  char* ws = (char*)d_ws;
  us*    Xbf  = (us*)(ws);
  us*    Wbf  = (us*)(ws + 4  * 1024 * 1024);
  us*    Wobf = (us*)(ws + 12 * 1024 * 1024);
  us*    Qb   = (us*)(ws + 14 * 1024 * 1024);
  us*    Kb   = (us*)(ws + 18 * 1024 * 1024);
  us*    Vt   = (us*)(ws + 22 * 1024 * 1024);
  float* G    = (float*)(ws + 26 * 1024 * 1024);
  us*    Ybf  = (us*)(ws + 34 * 1024 * 1024);
  float* lpart= (float*)(ws + (size_t)38 * 1024 * 1024);   // 512 KB
  us*    E    = (us*)   (ws + (size_t)40 * 1024 * 1024);   // 64 MB bf16
  if (ws_size < (size_t)104 * 1024 * 1024) return;

  prep_k<<<dim3(7168), dim3(256), 0, stream>>>(x, wproj, wg, wo, Xbf, Wbf, Wobf);
  gemm_qkvg_k<<<dim3(512), dim3(256), 0, stream>>>(Xbf, Wbf, Qb, Kb, Vt, G, bg);
  qke_k<<<dim3(1024), dim3(512), 0, stream>>>(Qb, Kb, bias, E, lpart);
  pv_k<<<dim3(1024), dim3(256), 0, stream>>>(E, Vt, lpart, G, outa, Ybf);
  gemm_out_k<<<dim3(128), dim3(256), 0, stream>>>(Ybf, Wobf, bo, outy);
}